// Round 2
// baseline (1811.942 us; speedup 1.0000x reference)
//
#include <hip/hip_runtime.h>
#include <hip/hip_bf16.h>

typedef unsigned short u16;
typedef __attribute__((ext_vector_type(4))) float f32x4;
typedef __attribute__((ext_vector_type(8))) short bf16x8;

typedef const __attribute__((address_space(1))) void GV;
typedef __attribute__((address_space(3))) void LV;
#define GLOAD16(g, l) __builtin_amdgcn_global_load_lds((GV*)(g), (LV*)(l), 16, 0, 0)

__device__ __forceinline__ float b2f(u16 u) {
    union { float f; unsigned int i; } v; v.i = ((unsigned int)u) << 16; return v.f;
}
__device__ __forceinline__ u16 f2b(float f) {
    union { float f; unsigned int i; } v; v.f = f;
    unsigned int x = v.i;
    return (u16)((x + 0x7fffu + ((x >> 16) & 1u)) >> 16);
}

// ---------------------------------------------------------------- K1: 3-NN
__global__ void knn_kernel(const float* __restrict__ xyz1, const float* __restrict__ xyz2,
                           int* __restrict__ idx_out, float* __restrict__ w_out) {
    __shared__ float4 spt[2048];
    int b = blockIdx.y;
    int tid = threadIdx.x;
    const float* p2 = xyz2 + (size_t)b * 3 * 2048;
    for (int s = tid; s < 2048; s += 256) {
        float x = p2[s], y = p2[2048 + s], z = p2[4096 + s];
        spt[s] = make_float4(x, y, z, (x * x + y * y) + z * z);
    }
    __syncthreads();
    int n = blockIdx.x * 256 + tid;
    const float* p1 = xyz1 + (size_t)b * 3 * 8192;
    float qx = p1[n], qy = p1[8192 + n], qz = p1[16384 + n];
    float qn = (qx * qx + qy * qy) + qz * qz;
    float d0 = 3.4e38f, d1 = 3.4e38f, d2 = 3.4e38f;
    int i0 = 0, i1 = 0, i2 = 0;
#pragma unroll 4
    for (int s = 0; s < 2048; ++s) {
        float4 p = spt[s];
        float dot = (qx * p.x + qy * p.y) + qz * p.z;
        float d = (-2.f * dot + qn) + p.w;   // reference op order
        if (d < d2) {
            if (d < d1) {
                if (d < d0) { d2 = d1; i2 = i1; d1 = d0; i1 = i0; d0 = d; i0 = s; }
                else        { d2 = d1; i2 = i1; d1 = d;  i1 = s; }
            } else          { d2 = d;  i2 = s; }
        }
    }
    float r0 = 1.f / (d0 + 1e-8f), r1 = 1.f / (d1 + 1e-8f), r2 = 1.f / (d2 + 1e-8f);
    float inv = 1.f / (r0 + r1 + r2);
    size_t base = ((size_t)b * 8192 + n) * 3;
    idx_out[base] = i0; idx_out[base + 1] = i1; idx_out[base + 2] = i2;
    w_out[base] = r0 * inv; w_out[base + 1] = r1 * inv; w_out[base + 2] = r2 * inv;
}

// ------------------------------------------- K2: build X0^T [B][N][384] bf16
__global__ void build_x0_kernel(const float* __restrict__ points1, const float* __restrict__ points2,
                                const int* __restrict__ idx, const float* __restrict__ wgt,
                                u16* __restrict__ x0t) {
    __shared__ u16 tile[64][392];   // row stride 784B (16B-aligned)
    int b = blockIdx.y;
    int n0 = blockIdx.x * 64;
    int tid = threadIdx.x, lane = tid & 63, wv = tid >> 6;
    const float* p1 = points1 + (size_t)b * 128 * 8192;
    for (int c = wv; c < 128; c += 4)
        tile[lane][c] = f2b(p1[(size_t)c * 8192 + n0 + lane]);
    size_t ib = ((size_t)b * 8192 + n0 + lane) * 3;
    int j0 = idx[ib], j1 = idx[ib + 1], j2 = idx[ib + 2];
    float w0 = wgt[ib], w1 = wgt[ib + 1], w2 = wgt[ib + 2];
    const float* p2 = points2 + (size_t)b * 256 * 2048;
    for (int c = wv; c < 256; c += 4) {
        const float* row = p2 + (size_t)c * 2048;
        float v = w0 * row[j0] + w1 * row[j1] + w2 * row[j2];
        tile[lane][128 + c] = f2b(v);
    }
    __syncthreads();
    for (int q = tid; q < 64 * 48; q += 256) {
        int r = q / 48, c8 = q % 48;
        uint4 vv = *(const uint4*)&tile[r][c8 * 8];
        *(uint4*)&x0t[((size_t)b * 8192 + n0 + r) * 384 + c8 * 8] = vv;
    }
}

// --------------------------------------------- weight f32 -> bf16 converter
__global__ void cvt_kernel(const float* __restrict__ src, u16* __restrict__ dst, int n) {
    int i = blockIdx.x * 256 + threadIdx.x;
    if (i < n) dst[i] = f2b(src[i]);
}

// ------------------------------------- K5: FiLM params  film[b][0:256]=scale, [256:512]=shift
__global__ void film_kernel(const float* __restrict__ t_emb, const float* __restrict__ c_emb,
                            const float* __restrict__ tw, const float* __restrict__ tb,
                            const float* __restrict__ cw, const float* __restrict__ cb,
                            float* __restrict__ film) {
    __shared__ float te[256], ce[256];
    int b = blockIdx.x, tid = threadIdx.x;
    te[tid] = t_emb[b * 256 + tid];
    ce[tid] = c_emb[b * 256 + tid];
    __syncthreads();
    int j = tid + blockIdx.y * 256;   // 0..511
    const float* twr = tw + (size_t)j * 256;
    const float* cwr = cw + (size_t)j * 256;
    float s = 0.f;
    for (int k = 0; k < 256; ++k) s += te[k] * twr[k] + ce[k] * cwr[k];
    s += tb[j] + cb[j];
    film[b * 512 + j] = s;
}

// ------------------------------------------------- K3: GEMM (channel-last)
// Out[b][n][o] = sum_c At[b][n][c] * W[o][c] + bias[o]; fused GN-stat atomics.
__global__ __launch_bounds__(256) void gemm_kernel(
        const u16* __restrict__ At, const u16* __restrict__ W, const float* __restrict__ bias,
        u16* __restrict__ Out, float* __restrict__ stats,
        int K, int M, int gshift) {
    __shared__ u16 lA[128 * 32];
    __shared__ u16 lB[128 * 32];
    int b = blockIdx.z;
    int n0 = blockIdx.x * 128, o0 = blockIdx.y * 128;
    int tid = threadIdx.x, lane = tid & 63, wv = tid >> 6;
    int wn = wv & 1, wo = wv >> 1;
    f32x4 acc[4][4];
#pragma unroll
    for (int i = 0; i < 4; i++)
#pragma unroll
        for (int j = 0; j < 4; j++) acc[i][j] = (f32x4){0.f, 0.f, 0.f, 0.f};

    const u16* aRow = At + ((size_t)b * 8192 + n0) * K;
    const u16* wRow = W + (size_t)o0 * K;
    int sr = lane >> 2;
    int sc = (lane & 3) * 8;
    int nK = K >> 5;
    for (int kt = 0; kt < nK; ++kt) {
        int c0 = kt << 5;
#pragma unroll
        for (int j = 0; j < 2; j++) {
            int r = wv * 32 + j * 16 + sr;
            GLOAD16(aRow + (size_t)r * K + c0 + sc, &lA[(wv * 32 + j * 16) * 32]);
            GLOAD16(wRow + (size_t)r * K + c0 + sc, &lB[(wv * 32 + j * 16) * 32]);
        }
        __syncthreads();
        bf16x8 af[4], bfr[4];
#pragma unroll
        for (int mf = 0; mf < 4; mf++)
            af[mf] = *(const bf16x8*)&lA[(wn * 64 + mf * 16 + (lane & 15)) * 32 + (lane >> 4) * 8];
#pragma unroll
        for (int nf = 0; nf < 4; nf++)
            bfr[nf] = *(const bf16x8*)&lB[(wo * 64 + nf * 16 + (lane & 15)) * 32 + (lane >> 4) * 8];
#pragma unroll
        for (int mf = 0; mf < 4; mf++)
#pragma unroll
            for (int nf = 0; nf < 4; nf++)
                acc[mf][nf] = __builtin_amdgcn_mfma_f32_16x16x32_bf16(af[mf], bfr[nf], acc[mf][nf], 0, 0, 0);
        __syncthreads();
    }
#pragma unroll
    for (int nf = 0; nf < 4; nf++) {
        int o = o0 + wo * 64 + nf * 16 + (lane & 15);
        float bv = bias[o];
        float s1 = 0.f, s2 = 0.f;
#pragma unroll
        for (int mf = 0; mf < 4; mf++)
#pragma unroll
            for (int r = 0; r < 4; r++) {
                float v = acc[mf][nf][r] + bv;
                acc[mf][nf][r] = v;
                s1 += v; s2 += v * v;
            }
#pragma unroll
        for (int off = 32; off > 0; off >>= 1) {
            s1 += __shfl_xor(s1, off, 64);
            s2 += __shfl_xor(s2, off, 64);
        }
        if (lane == 0) {
            int g = o >> gshift;
            atomicAdd(&stats[((size_t)b * 8 + g) * 2 + 0], s1);
            atomicAdd(&stats[((size_t)b * 8 + g) * 2 + 1], s2);
        }
    }
#pragma unroll
    for (int mf = 0; mf < 4; mf++) {
        int nbase = n0 + wn * 64 + mf * 16 + (lane >> 4) * 4;
#pragma unroll
        for (int r = 0; r < 4; r++) {
            size_t rowoff = ((size_t)b * 8192 + nbase + r) * M + o0 + wo * 64 + (lane & 15);
#pragma unroll
            for (int nf = 0; nf < 4; nf++)
                Out[rowoff + nf * 16] = f2b(acc[mf][nf][r]);
        }
    }
}

// -------------------------------------------- K4: in-place GroupNorm (+SiLU)
__global__ void gn_act_kernel(u16* __restrict__ Y, const float* __restrict__ gw, const float* __restrict__ gb,
                              const float* __restrict__ stats, int c8shift, int gshift,
                              float invCnt, int do_silu) {
    size_t total = ((size_t)8 * 8192) << c8shift;
    size_t stride = (size_t)gridDim.x * 256;
    for (size_t t = (size_t)blockIdx.x * 256 + threadIdx.x; t < total; t += stride) {
        size_t row = t >> c8shift;
        int c0 = (int)(t & (((size_t)1 << c8shift) - 1)) << 3;
        int b = (int)(row >> 13);
        int g = c0 >> gshift;
        float sum = stats[((size_t)b * 8 + g) * 2], ssq = stats[((size_t)b * 8 + g) * 2 + 1];
        float m = sum * invCnt;
        float rstd = rsqrtf(fmaxf(ssq * invCnt - m * m, 0.f) + 1e-5f);
        u16* p = Y + (row << (c8shift + 3)) + c0;
        uint4 v4 = *(const uint4*)p;
        u16* vu = (u16*)&v4;
#pragma unroll
        for (int j = 0; j < 8; j++) {
            int c = c0 + j;
            float v = (b2f(vu[j]) - m) * rstd * gw[c] + gb[c];
            if (do_silu) v = v / (1.f + __expf(-v));
            vu[j] = f2b(v);
        }
        *(uint4*)p = v4;
    }
}

// ----------------------- K6: GN2 + FiLM + residual, transpose to [B][C][N] f32
__global__ void final_kernel(const u16* __restrict__ Y2, const u16* __restrict__ X,
                             const float* __restrict__ g2w, const float* __restrict__ g2b,
                             const float* __restrict__ stats, const float* __restrict__ film,
                             float* __restrict__ out) {
    __shared__ float tile[64][257];
    int b = blockIdx.y, n0 = blockIdx.x * 64, tid = threadIdx.x;
    const float invCnt = 1.f / (32.f * 8192.f);
    for (int q = tid; q < 64 * 32; q += 256) {
        int nr = q >> 5, c8 = q & 31, c0 = c8 * 8;
        int g = c0 >> 5;
        float sum = stats[((size_t)b * 8 + g) * 2], ssq = stats[((size_t)b * 8 + g) * 2 + 1];
        float m = sum * invCnt, rstd = rsqrtf(fmaxf(ssq * invCnt - m * m, 0.f) + 1e-5f);
        size_t base = ((size_t)b * 8192 + n0 + nr) * 256 + c0;
        uint4 yv = *(const uint4*)(Y2 + base);
        uint4 xv = *(const uint4*)(X + base);
        const u16* yy = (const u16*)&yv;
        const u16* xx = (const u16*)&xv;
#pragma unroll
        for (int j = 0; j < 8; j++) {
            int c = c0 + j;
            float v = (b2f(yy[j]) - m) * rstd * g2w[c] + g2b[c];
            v = v * (1.f + film[b * 512 + c]) + film[b * 512 + 256 + c] + b2f(xx[j]);
            tile[nr][c] = v;
        }
    }
    __syncthreads();
    for (int q = tid; q < 256 * 16; q += 256) {
        int c = q >> 4, n4 = q & 15;
        float4 o;
        o.x = tile[n4 * 4 + 0][c];
        o.y = tile[n4 * 4 + 1][c];
        o.z = tile[n4 * 4 + 2][c];
        o.w = tile[n4 * 4 + 3][c];
        *(float4*)&out[((size_t)b * 256 + c) * 8192 + n0 + n4 * 4] = o;
    }
}

// ---------------------------------------------------------------------------
extern "C" void kernel_launch(void* const* d_in, const int* in_sizes, int n_in,
                              void* d_out, int out_size, void* d_ws, size_t ws_size,
                              hipStream_t stream) {
    const float* xyz1    = (const float*)d_in[0];
    const float* points1 = (const float*)d_in[1];
    const float* xyz2    = (const float*)d_in[2];
    const float* points2 = (const float*)d_in[3];
    const float* t_emb   = (const float*)d_in[4];
    const float* c_emb   = (const float*)d_in[5];
    const float* mlp_w   = (const float*)d_in[6];
    const float* mlp_b   = (const float*)d_in[7];
    const float* mlp_gw  = (const float*)d_in[8];
    const float* mlp_gb  = (const float*)d_in[9];
    const float* c1w     = (const float*)d_in[10];
    const float* c1b     = (const float*)d_in[11];
    const float* g1w     = (const float*)d_in[12];
    const float* g1b     = (const float*)d_in[13];
    const float* c2w     = (const float*)d_in[14];
    const float* c2b     = (const float*)d_in[15];
    const float* g2w     = (const float*)d_in[16];
    const float* g2b     = (const float*)d_in[17];
    const float* tw      = (const float*)d_in[18];
    const float* tb      = (const float*)d_in[19];
    const float* cw      = (const float*)d_in[20];
    const float* cb      = (const float*)d_in[21];

    char* ws = (char*)d_ws;
    int*   idx   = (int*)ws;                       //   786,432 B
    float* wgt   = (float*)(ws + 786432);          //   786,432 B
    float* stats = (float*)(ws + 1572864);         //   1,536 B
    float* film  = (float*)(ws + 1576960);         //   16,384 B
    u16* wb_mlp  = (u16*)(ws + 1593344);           //   196,608 B
    u16* wb_c1   = (u16*)(ws + 1789952);           //   524,288 B
    u16* wb_c2   = (u16*)(ws + 2314240);           //   524,288 B
    u16* X0t = (u16*)(ws + 4194304);               //  50,331,648 B  [B][N][384]
    u16* Y1t = (u16*)(ws + 54525952);              //  33,554,432 B  [B][N][256]
    u16* H1t = (u16*)(ws + 88080384);              // 134,217,728 B [B][N][1024]
    u16* Y2t = X0t;   // X0t dead after GEMM1
    float* out = (float*)d_out;

    hipMemsetAsync(stats, 0, 384 * sizeof(float), stream);
    cvt_kernel<<<384, 256, 0, stream>>>(mlp_w, wb_mlp, 98304);
    cvt_kernel<<<1024, 256, 0, stream>>>(c1w, wb_c1, 262144);
    cvt_kernel<<<1024, 256, 0, stream>>>(c2w, wb_c2, 262144);
    knn_kernel<<<dim3(32, 8), 256, 0, stream>>>(xyz1, xyz2, idx, wgt);
    build_x0_kernel<<<dim3(128, 8), 256, 0, stream>>>(points1, points2, idx, wgt, X0t);
    film_kernel<<<dim3(8, 2), 256, 0, stream>>>(t_emb, c_emb, tw, tb, cw, cb, film);
    // stage 1: conv(384->256) + GN(gs=32) + SiLU  -> identity X
    gemm_kernel<<<dim3(64, 2, 8), 256, 0, stream>>>(X0t, wb_mlp, mlp_b, Y1t, stats, 384, 256, 5);
    gn_act_kernel<<<1024, 256, 0, stream>>>(Y1t, mlp_gw, mlp_gb, stats, 5, 5, 1.f / (32.f * 8192.f), 1);
    // stage 2: conv(256->1024) + GN(gs=128) + SiLU
    gemm_kernel<<<dim3(64, 8, 8), 256, 0, stream>>>(Y1t, wb_c1, c1b, H1t, stats + 128, 256, 1024, 7);
    gn_act_kernel<<<2048, 256, 0, stream>>>(H1t, g1w, g1b, stats + 128, 7, 7, 1.f / (128.f * 8192.f), 1);
    // stage 3: conv(1024->256); GN2 + FiLM + residual fused into final
    gemm_kernel<<<dim3(64, 2, 8), 256, 0, stream>>>(H1t, wb_c2, c2b, Y2t, stats + 256, 1024, 256, 5);
    final_kernel<<<dim3(128, 8), 256, 0, stream>>>(Y2t, Y1t, g2w, g2b, stats + 256, film, out);
}

// Round 3
// 796.710 us; speedup vs baseline: 2.2743x; 2.2743x over previous
//
#include <hip/hip_runtime.h>
#include <hip/hip_bf16.h>

typedef unsigned short u16;
typedef __attribute__((ext_vector_type(4))) float f32x4;
typedef __attribute__((ext_vector_type(8))) short bf16x8;

typedef const __attribute__((address_space(1))) void GV;
typedef __attribute__((address_space(3))) void LV;
#define GLOAD16(g, l) __builtin_amdgcn_global_load_lds((GV*)(g), (LV*)(l), 16, 0, 0)

__device__ __forceinline__ float b2f(u16 u) {
    union { float f; unsigned int i; } v; v.i = ((unsigned int)u) << 16; return v.f;
}
__device__ __forceinline__ u16 f2b(float f) {
    union { float f; unsigned int i; } v; v.f = f;
    unsigned int x = v.i;
    return (u16)((x + 0x7fffu + ((x >> 16) & 1u)) >> 16);
}

// ---------------------------------------------------------------- K1: 3-NN
__global__ void knn_kernel(const float* __restrict__ xyz1, const float* __restrict__ xyz2,
                           int* __restrict__ idx_out, float* __restrict__ w_out) {
    __shared__ float4 spt[2048];
    int b = blockIdx.y;
    int tid = threadIdx.x;
    const float* p2 = xyz2 + (size_t)b * 3 * 2048;
    for (int s = tid; s < 2048; s += 256) {
        float x = p2[s], y = p2[2048 + s], z = p2[4096 + s];
        spt[s] = make_float4(x, y, z, (x * x + y * y) + z * z);
    }
    __syncthreads();
    int n = blockIdx.x * 256 + tid;
    const float* p1 = xyz1 + (size_t)b * 3 * 8192;
    float qx = p1[n], qy = p1[8192 + n], qz = p1[16384 + n];
    float qn = (qx * qx + qy * qy) + qz * qz;
    float d0 = 3.4e38f, d1 = 3.4e38f, d2 = 3.4e38f;
    int i0 = 0, i1 = 0, i2 = 0;
#pragma unroll 4
    for (int s = 0; s < 2048; ++s) {
        float4 p = spt[s];
        float dot = (qx * p.x + qy * p.y) + qz * p.z;
        float d = (-2.f * dot + qn) + p.w;   // reference op order
        if (d < d2) {
            if (d < d1) {
                if (d < d0) { d2 = d1; i2 = i1; d1 = d0; i1 = i0; d0 = d; i0 = s; }
                else        { d2 = d1; i2 = i1; d1 = d;  i1 = s; }
            } else          { d2 = d;  i2 = s; }
        }
    }
    float r0 = 1.f / (d0 + 1e-8f), r1 = 1.f / (d1 + 1e-8f), r2 = 1.f / (d2 + 1e-8f);
    float inv = 1.f / (r0 + r1 + r2);
    size_t base = ((size_t)b * 8192 + n) * 3;
    idx_out[base] = i0; idx_out[base + 1] = i1; idx_out[base + 2] = i2;
    w_out[base] = r0 * inv; w_out[base + 1] = r1 * inv; w_out[base + 2] = r2 * inv;
}

// ------------------------------------------- K2: build X0^T [B][N][384] bf16
__global__ void build_x0_kernel(const float* __restrict__ points1, const float* __restrict__ points2,
                                const int* __restrict__ idx, const float* __restrict__ wgt,
                                u16* __restrict__ x0t) {
    __shared__ u16 tile[64][392];
    int b = blockIdx.y;
    int n0 = blockIdx.x * 64;
    int tid = threadIdx.x, lane = tid & 63, wv = tid >> 6;
    const float* p1 = points1 + (size_t)b * 128 * 8192;
    for (int c = wv; c < 128; c += 4)
        tile[lane][c] = f2b(p1[(size_t)c * 8192 + n0 + lane]);
    size_t ib = ((size_t)b * 8192 + n0 + lane) * 3;
    int j0 = idx[ib], j1 = idx[ib + 1], j2 = idx[ib + 2];
    float w0 = wgt[ib], w1 = wgt[ib + 1], w2 = wgt[ib + 2];
    const float* p2 = points2 + (size_t)b * 256 * 2048;
    for (int c = wv; c < 256; c += 4) {
        const float* row = p2 + (size_t)c * 2048;
        float v = w0 * row[j0] + w1 * row[j1] + w2 * row[j2];
        tile[lane][128 + c] = f2b(v);
    }
    __syncthreads();
    for (int q = tid; q < 64 * 48; q += 256) {
        int r = q / 48, c8 = q % 48;
        uint4 vv = *(const uint4*)&tile[r][c8 * 8];
        *(uint4*)&x0t[((size_t)b * 8192 + n0 + r) * 384 + c8 * 8] = vv;
    }
}

// --------------------------------------------- weight f32 -> bf16 converter
__global__ void cvt_kernel(const float* __restrict__ src, u16* __restrict__ dst, int n) {
    int i = blockIdx.x * 256 + threadIdx.x;
    if (i < n) dst[i] = f2b(src[i]);
}

// ------------------------------------- K5: FiLM params
__global__ void film_kernel(const float* __restrict__ t_emb, const float* __restrict__ c_emb,
                            const float* __restrict__ tw, const float* __restrict__ tb,
                            const float* __restrict__ cw, const float* __restrict__ cb,
                            float* __restrict__ film) {
    __shared__ float te[256], ce[256];
    int b = blockIdx.x, tid = threadIdx.x;
    te[tid] = t_emb[b * 256 + tid];
    ce[tid] = c_emb[b * 256 + tid];
    __syncthreads();
    int j = tid + blockIdx.y * 256;
    const float* twr = tw + (size_t)j * 256;
    const float* cwr = cw + (size_t)j * 256;
    float s = 0.f;
    for (int k = 0; k < 256; ++k) s += te[k] * twr[k] + ce[k] * cwr[k];
    s += tb[j] + cb[j];
    film[b * 512 + j] = s;
}

// ------------------------------------------------- K3: GEMM (channel-last)
// Out[b][n][o] = sum_c At[b][n][c] * W[o][c] + bias[o]
// 128x128 tile, BK=64, XOR-swizzled LDS (ps = ls ^ (row&7)), per-block GN
// partials -> part[(b*8+g)*2+s][64] (non-atomic, fully overwritten).
__global__ __launch_bounds__(256) void gemm_kernel(
        const u16* __restrict__ At, const u16* __restrict__ W, const float* __restrict__ bias,
        u16* __restrict__ Out, float* __restrict__ part,
        int K, int M, int gshift) {
    __shared__ u16 lA[128 * 64];   // 16KB: 16 panels of (8 rows x 128B), swizzled
    __shared__ u16 lB[128 * 64];
    __shared__ float bpart[4][2];
    int b = blockIdx.z;
    int n0 = blockIdx.x * 128, o0 = blockIdx.y * 128;
    int tid = threadIdx.x, lane = tid & 63, wv = tid >> 6;
    int wn = wv & 1, wo = wv >> 1;
    if (tid < 8) ((float*)bpart)[tid] = 0.f;
    f32x4 acc[4][4];
#pragma unroll
    for (int i = 0; i < 4; i++)
#pragma unroll
        for (int j = 0; j < 4; j++) acc[i][j] = (f32x4){0.f, 0.f, 0.f, 0.f};

    const u16* aRow = At + ((size_t)b * 8192 + n0) * K;
    const u16* wRow = W + (size_t)o0 * K;
    // staging: lane l writes LDS byte l*16 of its panel -> row rl=l>>3, slot ps=l&7
    // source colslot pre-swizzled: cs = ps ^ rl (involution matches read-side XOR)
    int rl = lane >> 3;
    int csw = ((lane & 7) ^ rl) * 8;   // u16 units
    int nK = K >> 6;
    for (int kt = 0; kt < nK; ++kt) {
        int c0 = kt << 6;
#pragma unroll
        for (int p4 = 0; p4 < 4; p4++) {
            int p = wv * 4 + p4;
            GLOAD16(aRow + (size_t)(p * 8 + rl) * K + c0 + csw, &lA[p * 512]);
            GLOAD16(wRow + (size_t)(p * 8 + rl) * K + c0 + csw, &lB[p * 512]);
        }
        __syncthreads();
#pragma unroll
        for (int kk = 0; kk < 2; kk++) {
            bf16x8 af[4], bfr[4];
#pragma unroll
            for (int mf = 0; mf < 4; mf++) {
                int R = wn * 64 + mf * 16 + (lane & 15);
                af[mf] = *(const bf16x8*)&lA[R * 64 + ((kk * 4 + (lane >> 4)) ^ (R & 7)) * 8];
            }
#pragma unroll
            for (int nf = 0; nf < 4; nf++) {
                int R = wo * 64 + nf * 16 + (lane & 15);
                bfr[nf] = *(const bf16x8*)&lB[R * 64 + ((kk * 4 + (lane >> 4)) ^ (R & 7)) * 8];
            }
#pragma unroll
            for (int mf = 0; mf < 4; mf++)
#pragma unroll
                for (int nf = 0; nf < 4; nf++)
                    acc[mf][nf] = __builtin_amdgcn_mfma_f32_16x16x32_bf16(af[mf], bfr[nf], acc[mf][nf], 0, 0, 0);
        }
        __syncthreads();
    }
    // epilogue: bias, per-block GN partials (LDS), store bf16
#pragma unroll
    for (int nf = 0; nf < 4; nf++) {
        int od = wo * 64 + nf * 16;           // o offset within block
        float bv = bias[o0 + od + (lane & 15)];
        float s1 = 0.f, s2 = 0.f;
#pragma unroll
        for (int mf = 0; mf < 4; mf++)
#pragma unroll
            for (int r = 0; r < 4; r++) {
                float v = acc[mf][nf][r] + bv;
                acc[mf][nf][r] = v;
                s1 += v; s2 += v * v;
            }
#pragma unroll
        for (int off = 32; off > 0; off >>= 1) {
            s1 += __shfl_xor(s1, off, 64);
            s2 += __shfl_xor(s2, off, 64);
        }
        if (lane == 0) {
            int gl = od >> gshift;            // 0..3
            atomicAdd(&bpart[gl][0], s1);
            atomicAdd(&bpart[gl][1], s2);
        }
    }
#pragma unroll
    for (int mf = 0; mf < 4; mf++) {
        int nbase = n0 + wn * 64 + mf * 16 + (lane >> 4) * 4;
#pragma unroll
        for (int r = 0; r < 4; r++) {
            size_t rowoff = ((size_t)b * 8192 + nbase + r) * M + o0 + wo * 64 + (lane & 15);
#pragma unroll
            for (int nf = 0; nf < 4; nf++)
                Out[rowoff + nf * 16] = f2b(acc[mf][nf][r]);
        }
    }
    __syncthreads();
    int nlg = 128 >> gshift;                  // groups per block (4 or 1)
    if (tid < 2 * nlg) {
        int gl = tid >> 1, s = tid & 1;
        int g = (o0 >> gshift) + gl;
        part[(((size_t)b * 8 + g) * 2 + s) * 64 + blockIdx.x] = bpart[gl][s];
    }
}

// ------------------------------------- K3b: reduce partials -> stats[128]
__global__ void gn_reduce_kernel(const float* __restrict__ part, float* __restrict__ stats) {
    int t = threadIdx.x;   // 0..127
    const float4* p = (const float4*)(part + (size_t)t * 64);
    float s = 0.f;
#pragma unroll
    for (int i = 0; i < 16; i++) { float4 v = p[i]; s += (v.x + v.y) + (v.z + v.w); }
    stats[t] = s;
}

// -------------------------------------------- K4: in-place GroupNorm (+SiLU)
__global__ void gn_act_kernel(u16* __restrict__ Y, const float* __restrict__ gw, const float* __restrict__ gb,
                              const float* __restrict__ stats, int c8shift, int gshift,
                              float invCnt, int do_silu) {
    size_t total = ((size_t)8 * 8192) << c8shift;
    size_t stride = (size_t)gridDim.x * 256;
    for (size_t t = (size_t)blockIdx.x * 256 + threadIdx.x; t < total; t += stride) {
        size_t row = t >> c8shift;
        int c0 = (int)(t & (((size_t)1 << c8shift) - 1)) << 3;
        int b = (int)(row >> 13);
        int g = c0 >> gshift;
        float sum = stats[((size_t)b * 8 + g) * 2], ssq = stats[((size_t)b * 8 + g) * 2 + 1];
        float m = sum * invCnt;
        float rstd = rsqrtf(fmaxf(ssq * invCnt - m * m, 0.f) + 1e-5f);
        u16* p = Y + (row << (c8shift + 3)) + c0;
        uint4 v4 = *(const uint4*)p;
        u16* vu = (u16*)&v4;
#pragma unroll
        for (int j = 0; j < 8; j++) {
            int c = c0 + j;
            float v = (b2f(vu[j]) - m) * rstd * gw[c] + gb[c];
            if (do_silu) v = v / (1.f + __expf(-v));
            vu[j] = f2b(v);
        }
        *(uint4*)p = v4;
    }
}

// ----------------------- K6: GN2 + FiLM + residual, transpose to [B][C][N] f32
__global__ void final_kernel(const u16* __restrict__ Y2, const u16* __restrict__ X,
                             const float* __restrict__ g2w, const float* __restrict__ g2b,
                             const float* __restrict__ stats, const float* __restrict__ film,
                             float* __restrict__ out) {
    __shared__ float tile[64][257];
    int b = blockIdx.y, n0 = blockIdx.x * 64, tid = threadIdx.x;
    const float invCnt = 1.f / (32.f * 8192.f);
    for (int q = tid; q < 64 * 32; q += 256) {
        int nr = q >> 5, c8 = q & 31, c0 = c8 * 8;
        int g = c0 >> 5;
        float sum = stats[((size_t)b * 8 + g) * 2], ssq = stats[((size_t)b * 8 + g) * 2 + 1];
        float m = sum * invCnt, rstd = rsqrtf(fmaxf(ssq * invCnt - m * m, 0.f) + 1e-5f);
        size_t base = ((size_t)b * 8192 + n0 + nr) * 256 + c0;
        uint4 yv = *(const uint4*)(Y2 + base);
        uint4 xv = *(const uint4*)(X + base);
        const u16* yy = (const u16*)&yv;
        const u16* xx = (const u16*)&xv;
#pragma unroll
        for (int j = 0; j < 8; j++) {
            int c = c0 + j;
            float v = (b2f(yy[j]) - m) * rstd * g2w[c] + g2b[c];
            v = v * (1.f + film[b * 512 + c]) + film[b * 512 + 256 + c] + b2f(xx[j]);
            tile[nr][c] = v;
        }
    }
    __syncthreads();
    for (int q = tid; q < 256 * 16; q += 256) {
        int c = q >> 4, n4 = q & 15;
        float4 o;
        o.x = tile[n4 * 4 + 0][c];
        o.y = tile[n4 * 4 + 1][c];
        o.z = tile[n4 * 4 + 2][c];
        o.w = tile[n4 * 4 + 3][c];
        *(float4*)&out[((size_t)b * 256 + c) * 8192 + n0 + n4 * 4] = o;
    }
}

// ---------------------------------------------------------------------------
extern "C" void kernel_launch(void* const* d_in, const int* in_sizes, int n_in,
                              void* d_out, int out_size, void* d_ws, size_t ws_size,
                              hipStream_t stream) {
    const float* xyz1    = (const float*)d_in[0];
    const float* points1 = (const float*)d_in[1];
    const float* xyz2    = (const float*)d_in[2];
    const float* points2 = (const float*)d_in[3];
    const float* t_emb   = (const float*)d_in[4];
    const float* c_emb   = (const float*)d_in[5];
    const float* mlp_w   = (const float*)d_in[6];
    const float* mlp_b   = (const float*)d_in[7];
    const float* mlp_gw  = (const float*)d_in[8];
    const float* mlp_gb  = (const float*)d_in[9];
    const float* c1w     = (const float*)d_in[10];
    const float* c1b     = (const float*)d_in[11];
    const float* g1w     = (const float*)d_in[12];
    const float* g1b     = (const float*)d_in[13];
    const float* c2w     = (const float*)d_in[14];
    const float* c2b     = (const float*)d_in[15];
    const float* g2w     = (const float*)d_in[16];
    const float* g2b     = (const float*)d_in[17];
    const float* tw      = (const float*)d_in[18];
    const float* tb      = (const float*)d_in[19];
    const float* cw      = (const float*)d_in[20];
    const float* cb      = (const float*)d_in[21];

    char* ws = (char*)d_ws;
    int*   idx    = (int*)ws;                      // 786,432 B
    float* wgt    = (float*)(ws + 786432);         // 786,432 B
    float* stats0 = (float*)(ws + 1572864);        // 512 B each
    float* stats1 = (float*)(ws + 1573376);
    float* stats2 = (float*)(ws + 1573888);
    float* film   = (float*)(ws + 1574400);        // 16,384 B
    float* part0  = (float*)(ws + 1590784);        // 32,768 B each
    float* part1  = (float*)(ws + 1623552);
    float* part2  = (float*)(ws + 1656320);
    u16* wb_mlp   = (u16*)(ws + 1689088);          // 196,608 B
    u16* wb_c1    = (u16*)(ws + 1885696);          // 524,288 B
    u16* wb_c2    = (u16*)(ws + 2409984);          // 524,288 B
    u16* X0t = (u16*)(ws + 4194304);               //  50,331,648 B [B][N][384]
    u16* Y1t = (u16*)(ws + 54525952);              //  33,554,432 B [B][N][256]
    u16* H1t = (u16*)(ws + 88080384);              // 134,217,728 B [B][N][1024]
    u16* Y2t = X0t;   // X0t dead after GEMM1
    float* out = (float*)d_out;

    cvt_kernel<<<384, 256, 0, stream>>>(mlp_w, wb_mlp, 98304);
    cvt_kernel<<<1024, 256, 0, stream>>>(c1w, wb_c1, 262144);
    cvt_kernel<<<1024, 256, 0, stream>>>(c2w, wb_c2, 262144);
    knn_kernel<<<dim3(32, 8), 256, 0, stream>>>(xyz1, xyz2, idx, wgt);
    build_x0_kernel<<<dim3(128, 8), 256, 0, stream>>>(points1, points2, idx, wgt, X0t);
    film_kernel<<<dim3(8, 2), 256, 0, stream>>>(t_emb, c_emb, tw, tb, cw, cb, film);
    // stage 1: conv(384->256) + GN(gs=32) + SiLU  -> identity X
    gemm_kernel<<<dim3(64, 2, 8), 256, 0, stream>>>(X0t, wb_mlp, mlp_b, Y1t, part0, 384, 256, 5);
    gn_reduce_kernel<<<1, 128, 0, stream>>>(part0, stats0);
    gn_act_kernel<<<1024, 256, 0, stream>>>(Y1t, mlp_gw, mlp_gb, stats0, 5, 5, 1.f / (32.f * 8192.f), 1);
    // stage 2: conv(256->1024) + GN(gs=128) + SiLU
    gemm_kernel<<<dim3(64, 8, 8), 256, 0, stream>>>(Y1t, wb_c1, c1b, H1t, part1, 256, 1024, 7);
    gn_reduce_kernel<<<1, 128, 0, stream>>>(part1, stats1);
    gn_act_kernel<<<2048, 256, 0, stream>>>(H1t, g1w, g1b, stats1, 7, 7, 1.f / (128.f * 8192.f), 1);
    // stage 3: conv(1024->256); GN2 + FiLM + residual fused into final
    gemm_kernel<<<dim3(64, 2, 8), 256, 0, stream>>>(H1t, wb_c2, c2b, Y2t, part2, 1024, 256, 5);
    gn_reduce_kernel<<<1, 128, 0, stream>>>(part2, stats2);
    final_kernel<<<dim3(128, 8), 256, 0, stream>>>(Y2t, Y1t, g2w, g2b, stats2, film, out);
}

// Round 4
// 559.493 us; speedup vs baseline: 3.2385x; 1.4240x over previous
//
#include <hip/hip_runtime.h>
#include <hip/hip_bf16.h>

typedef unsigned short u16;
typedef __attribute__((ext_vector_type(4))) float f32x4;
typedef __attribute__((ext_vector_type(8))) short bf16x8;

typedef const __attribute__((address_space(1))) void GV;
typedef __attribute__((address_space(3))) void LV;
#define GLOAD16(g, l) __builtin_amdgcn_global_load_lds((GV*)(g), (LV*)(l), 16, 0, 0)

__device__ __forceinline__ float b2f(u16 u) {
    union { float f; unsigned int i; } v; v.i = ((unsigned int)u) << 16; return v.f;
}
__device__ __forceinline__ u16 f2b(float f) {
    union { float f; unsigned int i; } v; v.f = f;
    unsigned int x = v.i;
    return (u16)((x + 0x7fffu + ((x >> 16) & 1u)) >> 16);
}

// ---------------------------------------------------------------- K1: 3-NN
__global__ void knn_kernel(const float* __restrict__ xyz1, const float* __restrict__ xyz2,
                           int* __restrict__ idx_out, float* __restrict__ w_out) {
    __shared__ float4 spt[2048];
    int b = blockIdx.y;
    int tid = threadIdx.x;
    const float* p2 = xyz2 + (size_t)b * 3 * 2048;
    for (int s = tid; s < 2048; s += 256) {
        float x = p2[s], y = p2[2048 + s], z = p2[4096 + s];
        spt[s] = make_float4(x, y, z, (x * x + y * y) + z * z);
    }
    __syncthreads();
    int n = blockIdx.x * 256 + tid;
    const float* p1 = xyz1 + (size_t)b * 3 * 8192;
    float qx = p1[n], qy = p1[8192 + n], qz = p1[16384 + n];
    float qn = (qx * qx + qy * qy) + qz * qz;
    float d0 = 3.4e38f, d1 = 3.4e38f, d2 = 3.4e38f;
    int i0 = 0, i1 = 0, i2 = 0;
#pragma unroll 4
    for (int s = 0; s < 2048; ++s) {
        float4 p = spt[s];
        float dot = (qx * p.x + qy * p.y) + qz * p.z;
        float d = (-2.f * dot + qn) + p.w;   // reference op order
        if (d < d2) {
            if (d < d1) {
                if (d < d0) { d2 = d1; i2 = i1; d1 = d0; i1 = i0; d0 = d; i0 = s; }
                else        { d2 = d1; i2 = i1; d1 = d;  i1 = s; }
            } else          { d2 = d;  i2 = s; }
        }
    }
    float r0 = 1.f / (d0 + 1e-8f), r1 = 1.f / (d1 + 1e-8f), r2 = 1.f / (d2 + 1e-8f);
    float inv = 1.f / (r0 + r1 + r2);
    size_t base = ((size_t)b * 8192 + n) * 3;
    idx_out[base] = i0; idx_out[base + 1] = i1; idx_out[base + 2] = i2;
    w_out[base] = r0 * inv; w_out[base + 1] = r1 * inv; w_out[base + 2] = r2 * inv;
}

// ------------------------------------------- K2: build X0^T [B][N][384] bf16
__global__ void build_x0_kernel(const float* __restrict__ points1, const float* __restrict__ points2,
                                const int* __restrict__ idx, const float* __restrict__ wgt,
                                u16* __restrict__ x0t) {
    __shared__ u16 tile[64][392];
    int b = blockIdx.y;
    int n0 = blockIdx.x * 64;
    int tid = threadIdx.x, lane = tid & 63, wv = tid >> 6;
    const float* p1 = points1 + (size_t)b * 128 * 8192;
    for (int c = wv; c < 128; c += 4)
        tile[lane][c] = f2b(p1[(size_t)c * 8192 + n0 + lane]);
    size_t ib = ((size_t)b * 8192 + n0 + lane) * 3;
    int j0 = idx[ib], j1 = idx[ib + 1], j2 = idx[ib + 2];
    float w0 = wgt[ib], w1 = wgt[ib + 1], w2 = wgt[ib + 2];
    const float* p2 = points2 + (size_t)b * 256 * 2048;
    for (int c = wv; c < 256; c += 4) {
        const float* row = p2 + (size_t)c * 2048;
        float v = w0 * row[j0] + w1 * row[j1] + w2 * row[j2];
        tile[lane][128 + c] = f2b(v);
    }
    __syncthreads();
    for (int q = tid; q < 64 * 48; q += 256) {
        int r = q / 48, c8 = q % 48;
        uint4 vv = *(const uint4*)&tile[r][c8 * 8];
        *(uint4*)&x0t[((size_t)b * 8192 + n0 + r) * 384 + c8 * 8] = vv;
    }
}

// --------------------------------------------- weight f32 -> bf16 converter
__global__ void cvt_kernel(const float* __restrict__ src, u16* __restrict__ dst, int n) {
    int i = blockIdx.x * 256 + threadIdx.x;
    if (i < n) dst[i] = f2b(src[i]);
}

// ------------------------------------- K5: FiLM params
__global__ void film_kernel(const float* __restrict__ t_emb, const float* __restrict__ c_emb,
                            const float* __restrict__ tw, const float* __restrict__ tb,
                            const float* __restrict__ cw, const float* __restrict__ cb,
                            float* __restrict__ film) {
    __shared__ float te[256], ce[256];
    int b = blockIdx.x, tid = threadIdx.x;
    te[tid] = t_emb[b * 256 + tid];
    ce[tid] = c_emb[b * 256 + tid];
    __syncthreads();
    int j = tid + blockIdx.y * 256;
    const float* twr = tw + (size_t)j * 256;
    const float* cwr = cw + (size_t)j * 256;
    float s = 0.f;
    for (int k = 0; k < 256; ++k) s += te[k] * twr[k] + ce[k] * cwr[k];
    s += tb[j] + cb[j];
    film[b * 512 + j] = s;
}

// ------------------------------------------------- K3: GEMM (channel-last)
__global__ __launch_bounds__(256) void gemm_kernel(
        const u16* __restrict__ At, const u16* __restrict__ W, const float* __restrict__ bias,
        u16* __restrict__ Out, float* __restrict__ part,
        int K, int M, int gshift) {
    __shared__ u16 lA[128 * 64];
    __shared__ u16 lB[128 * 64];
    __shared__ float bpart[4][2];
    int b = blockIdx.z;
    int n0 = blockIdx.x * 128, o0 = blockIdx.y * 128;
    int tid = threadIdx.x, lane = tid & 63, wv = tid >> 6;
    int wn = wv & 1, wo = wv >> 1;
    if (tid < 8) ((float*)bpart)[tid] = 0.f;
    f32x4 acc[4][4];
#pragma unroll
    for (int i = 0; i < 4; i++)
#pragma unroll
        for (int j = 0; j < 4; j++) acc[i][j] = (f32x4){0.f, 0.f, 0.f, 0.f};

    const u16* aRow = At + ((size_t)b * 8192 + n0) * K;
    const u16* wRow = W + (size_t)o0 * K;
    int rl = lane >> 3;
    int csw = ((lane & 7) ^ rl) * 8;
    int nK = K >> 6;
    for (int kt = 0; kt < nK; ++kt) {
        int c0 = kt << 6;
#pragma unroll
        for (int p4 = 0; p4 < 4; p4++) {
            int p = wv * 4 + p4;
            GLOAD16(aRow + (size_t)(p * 8 + rl) * K + c0 + csw, &lA[p * 512]);
            GLOAD16(wRow + (size_t)(p * 8 + rl) * K + c0 + csw, &lB[p * 512]);
        }
        __syncthreads();
#pragma unroll
        for (int kk = 0; kk < 2; kk++) {
            bf16x8 af[4], bfr[4];
#pragma unroll
            for (int mf = 0; mf < 4; mf++) {
                int R = wn * 64 + mf * 16 + (lane & 15);
                af[mf] = *(const bf16x8*)&lA[R * 64 + ((kk * 4 + (lane >> 4)) ^ (R & 7)) * 8];
            }
#pragma unroll
            for (int nf = 0; nf < 4; nf++) {
                int R = wo * 64 + nf * 16 + (lane & 15);
                bfr[nf] = *(const bf16x8*)&lB[R * 64 + ((kk * 4 + (lane >> 4)) ^ (R & 7)) * 8];
            }
#pragma unroll
            for (int mf = 0; mf < 4; mf++)
#pragma unroll
                for (int nf = 0; nf < 4; nf++)
                    acc[mf][nf] = __builtin_amdgcn_mfma_f32_16x16x32_bf16(af[mf], bfr[nf], acc[mf][nf], 0, 0, 0);
        }
        __syncthreads();
    }
#pragma unroll
    for (int nf = 0; nf < 4; nf++) {
        int od = wo * 64 + nf * 16;
        float bv = bias[o0 + od + (lane & 15)];
        float s1 = 0.f, s2 = 0.f;
#pragma unroll
        for (int mf = 0; mf < 4; mf++)
#pragma unroll
            for (int r = 0; r < 4; r++) {
                float v = acc[mf][nf][r] + bv;
                acc[mf][nf][r] = v;
                s1 += v; s2 += v * v;
            }
#pragma unroll
        for (int off = 32; off > 0; off >>= 1) {
            s1 += __shfl_xor(s1, off, 64);
            s2 += __shfl_xor(s2, off, 64);
        }
        if (lane == 0) {
            int gl = od >> gshift;
            atomicAdd(&bpart[gl][0], s1);
            atomicAdd(&bpart[gl][1], s2);
        }
    }
#pragma unroll
    for (int mf = 0; mf < 4; mf++) {
        int nbase = n0 + wn * 64 + mf * 16 + (lane >> 4) * 4;
#pragma unroll
        for (int r = 0; r < 4; r++) {
            size_t rowoff = ((size_t)b * 8192 + nbase + r) * M + o0 + wo * 64 + (lane & 15);
#pragma unroll
            for (int nf = 0; nf < 4; nf++)
                Out[rowoff + nf * 16] = f2b(acc[mf][nf][r]);
        }
    }
    __syncthreads();
    int nlg = 128 >> gshift;
    if (tid < 2 * nlg) {
        int gl = tid >> 1, s = tid & 1;
        int g = (o0 >> gshift) + gl;
        part[(((size_t)b * 8 + g) * 2 + s) * 64 + blockIdx.x] = bpart[gl][s];
    }
}

// ------------------------------------- K3b: reduce partials -> stats[128]
__global__ void gn_reduce_kernel(const float* __restrict__ part, float* __restrict__ stats) {
    int t = threadIdx.x;
    const float4* p = (const float4*)(part + (size_t)t * 64);
    float s = 0.f;
#pragma unroll
    for (int i = 0; i < 16; i++) { float4 v = p[i]; s += (v.x + v.y) + (v.z + v.w); }
    stats[t] = s;
}

// ------------------- K4: in-place GroupNorm + SiLU, fixed-channel threads
// thread owns channel-chunk c8 (8 ch) for all rows; params hoisted to regs.
__global__ void gn_act2_kernel(u16* __restrict__ Y, const float* __restrict__ gw,
                               const float* __restrict__ gb, const float* __restrict__ stats,
                               int c8bits, int gshift, float invCnt) {
    int t = blockIdx.x * 256 + threadIdx.x;
    int C8m = (1 << c8bits) - 1;
    int c8 = t & C8m;
    int c0 = c8 << 3;
    int g = c0 >> gshift;
    int row0 = t >> c8bits;
    int rowstep = (gridDim.x * 256) >> c8bits;
    float4 w0 = *(const float4*)(gw + c0), w1 = *(const float4*)(gw + c0 + 4);
    float4 b0 = *(const float4*)(gb + c0), b1 = *(const float4*)(gb + c0 + 4);
    float wv[8] = {w0.x, w0.y, w0.z, w0.w, w1.x, w1.y, w1.z, w1.w};
    float bv[8] = {b0.x, b0.y, b0.z, b0.w, b1.x, b1.y, b1.z, b1.w};
    float A[8], Bc[8];
    int bprev = -1;
    for (int row = row0; row < 65536; row += rowstep) {
        int b = row >> 13;           // wave-uniform
        if (b != bprev) {
            bprev = b;
            float sum = stats[(b * 8 + g) * 2], ssq = stats[(b * 8 + g) * 2 + 1];
            float m = sum * invCnt;
            float rstd = rsqrtf(fmaxf(ssq * invCnt - m * m, 0.f) + 1e-5f);
#pragma unroll
            for (int j = 0; j < 8; j++) { A[j] = rstd * wv[j]; Bc[j] = bv[j] - m * rstd * wv[j]; }
        }
        u16* p = Y + (((size_t)row << c8bits) << 3) + c0;
        uint4 v4 = *(const uint4*)p;
        u16* vu = (u16*)&v4;
#pragma unroll
        for (int j = 0; j < 8; j++) {
            float v = b2f(vu[j]) * A[j] + Bc[j];
            v = v * __builtin_amdgcn_rcpf(1.f + __expf(-v));   // silu
            vu[j] = f2b(v);
        }
        *(uint4*)p = v4;
    }
}

// ----------------------- K6: GN2 + FiLM + residual, transpose to [B][C][N] f32
__global__ void final_kernel(const u16* __restrict__ Y2, const u16* __restrict__ X,
                             const float* __restrict__ g2w, const float* __restrict__ g2b,
                             const float* __restrict__ stats, const float* __restrict__ film,
                             float* __restrict__ out) {
    __shared__ float tile[64][257];
    int b = blockIdx.y, n0 = blockIdx.x * 64, tid = threadIdx.x;
    const float invCnt = 1.f / (32.f * 8192.f);
    // per-thread fixed channel chunk: hoist everything into an affine
    int c8 = tid & 31, c0 = c8 << 3, g = c8 >> 2;
    float sum = stats[(b * 8 + g) * 2], ssq = stats[(b * 8 + g) * 2 + 1];
    float m = sum * invCnt, rstd = rsqrtf(fmaxf(ssq * invCnt - m * m, 0.f) + 1e-5f);
    float4 w0 = *(const float4*)(g2w + c0), w1 = *(const float4*)(g2w + c0 + 4);
    float4 q0 = *(const float4*)(g2b + c0), q1 = *(const float4*)(g2b + c0 + 4);
    float4 f0 = *(const float4*)(film + b * 512 + c0), f1 = *(const float4*)(film + b * 512 + c0 + 4);
    float4 h0 = *(const float4*)(film + b * 512 + 256 + c0), h1 = *(const float4*)(film + b * 512 + 256 + c0 + 4);
    float wv[8] = {w0.x, w0.y, w0.z, w0.w, w1.x, w1.y, w1.z, w1.w};
    float qv[8] = {q0.x, q0.y, q0.z, q0.w, q1.x, q1.y, q1.z, q1.w};
    float fs[8] = {f0.x, f0.y, f0.z, f0.w, f1.x, f1.y, f1.z, f1.w};
    float fh[8] = {h0.x, h0.y, h0.z, h0.w, h1.x, h1.y, h1.z, h1.w};
    float A[8], Bc[8];
#pragma unroll
    for (int j = 0; j < 8; j++) {
        float sc = 1.f + fs[j];
        A[j] = rstd * wv[j] * sc;
        Bc[j] = (qv[j] - m * rstd * wv[j]) * sc + fh[j];
    }
    int nrb = tid >> 5;
#pragma unroll
    for (int k = 0; k < 8; k++) {
        int nr = nrb + k * 8;
        size_t base = ((size_t)b * 8192 + n0 + nr) * 256 + c0;
        uint4 yv = *(const uint4*)(Y2 + base);
        uint4 xv = *(const uint4*)(X + base);
        const u16* yy = (const u16*)&yv;
        const u16* xx = (const u16*)&xv;
#pragma unroll
        for (int j = 0; j < 8; j++)
            tile[nr][c0 + j] = b2f(yy[j]) * A[j] + Bc[j] + b2f(xx[j]);
    }
    __syncthreads();
    for (int q = tid; q < 256 * 16; q += 256) {
        int c = q >> 4, n4 = q & 15;
        float4 o;
        o.x = tile[n4 * 4 + 0][c];
        o.y = tile[n4 * 4 + 1][c];
        o.z = tile[n4 * 4 + 2][c];
        o.w = tile[n4 * 4 + 3][c];
        *(float4*)&out[((size_t)b * 256 + c) * 8192 + n0 + n4 * 4] = o;
    }
}

// ---------------------------------------------------------------------------
extern "C" void kernel_launch(void* const* d_in, const int* in_sizes, int n_in,
                              void* d_out, int out_size, void* d_ws, size_t ws_size,
                              hipStream_t stream) {
    const float* xyz1    = (const float*)d_in[0];
    const float* points1 = (const float*)d_in[1];
    const float* xyz2    = (const float*)d_in[2];
    const float* points2 = (const float*)d_in[3];
    const float* t_emb   = (const float*)d_in[4];
    const float* c_emb   = (const float*)d_in[5];
    const float* mlp_w   = (const float*)d_in[6];
    const float* mlp_b   = (const float*)d_in[7];
    const float* mlp_gw  = (const float*)d_in[8];
    const float* mlp_gb  = (const float*)d_in[9];
    const float* c1w     = (const float*)d_in[10];
    const float* c1b     = (const float*)d_in[11];
    const float* g1w     = (const float*)d_in[12];
    const float* g1b     = (const float*)d_in[13];
    const float* c2w     = (const float*)d_in[14];
    const float* c2b     = (const float*)d_in[15];
    const float* g2w     = (const float*)d_in[16];
    const float* g2b     = (const float*)d_in[17];
    const float* tw      = (const float*)d_in[18];
    const float* tb      = (const float*)d_in[19];
    const float* cw      = (const float*)d_in[20];
    const float* cb      = (const float*)d_in[21];

    char* ws = (char*)d_ws;
    int*   idx    = (int*)ws;
    float* wgt    = (float*)(ws + 786432);
    float* stats0 = (float*)(ws + 1572864);
    float* stats1 = (float*)(ws + 1573376);
    float* stats2 = (float*)(ws + 1573888);
    float* film   = (float*)(ws + 1574400);
    float* part0  = (float*)(ws + 1590784);
    float* part1  = (float*)(ws + 1623552);
    float* part2  = (float*)(ws + 1656320);
    u16* wb_mlp   = (u16*)(ws + 1689088);
    u16* wb_c1    = (u16*)(ws + 1885696);
    u16* wb_c2    = (u16*)(ws + 2409984);
    u16* X0t = (u16*)(ws + 4194304);               //  50,331,648 B [B][N][384]
    u16* Y1t = (u16*)(ws + 54525952);              //  33,554,432 B [B][N][256]
    u16* H1t = (u16*)(ws + 88080384);              // 134,217,728 B [B][N][1024]
    u16* Y2t = X0t;
    float* out = (float*)d_out;

    cvt_kernel<<<384, 256, 0, stream>>>(mlp_w, wb_mlp, 98304);
    cvt_kernel<<<1024, 256, 0, stream>>>(c1w, wb_c1, 262144);
    cvt_kernel<<<1024, 256, 0, stream>>>(c2w, wb_c2, 262144);
    knn_kernel<<<dim3(32, 8), 256, 0, stream>>>(xyz1, xyz2, idx, wgt);
    build_x0_kernel<<<dim3(128, 8), 256, 0, stream>>>(points1, points2, idx, wgt, X0t);
    film_kernel<<<dim3(8, 2), 256, 0, stream>>>(t_emb, c_emb, tw, tb, cw, cb, film);
    // stage 1: conv(384->256) + GN(gs=32) + SiLU  -> identity X
    gemm_kernel<<<dim3(64, 2, 8), 256, 0, stream>>>(X0t, wb_mlp, mlp_b, Y1t, part0, 384, 256, 5);
    gn_reduce_kernel<<<1, 128, 0, stream>>>(part0, stats0);
    gn_act2_kernel<<<512, 256, 0, stream>>>(Y1t, mlp_gw, mlp_gb, stats0, 5, 5, 1.f / (32.f * 8192.f));
    // stage 2: conv(256->1024) + GN(gs=128) + SiLU
    gemm_kernel<<<dim3(64, 8, 8), 256, 0, stream>>>(Y1t, wb_c1, c1b, H1t, part1, 256, 1024, 7);
    gn_reduce_kernel<<<1, 128, 0, stream>>>(part1, stats1);
    gn_act2_kernel<<<2048, 256, 0, stream>>>(H1t, g1w, g1b, stats1, 7, 7, 1.f / (128.f * 8192.f));
    // stage 3: conv(1024->256); GN2 + FiLM + residual fused into final
    gemm_kernel<<<dim3(64, 2, 8), 256, 0, stream>>>(H1t, wb_c2, c2b, Y2t, part2, 1024, 256, 5);
    gn_reduce_kernel<<<1, 128, 0, stream>>>(part2, stats2);
    final_kernel<<<dim3(128, 8), 256, 0, stream>>>(Y2t, Y1t, g2w, g2b, stats2, film, out);
}

// Round 5
// 438.460 us; speedup vs baseline: 4.1325x; 1.2760x over previous
//
#include <hip/hip_runtime.h>
#include <hip/hip_bf16.h>

typedef unsigned short u16;
typedef __attribute__((ext_vector_type(4))) float f32x4;
typedef __attribute__((ext_vector_type(8))) short bf16x8;

typedef const __attribute__((address_space(1))) void GV;
typedef __attribute__((address_space(3))) void LV;
#define GLOAD16(g, l) __builtin_amdgcn_global_load_lds((GV*)(g), (LV*)(l), 16, 0, 0)

__device__ __forceinline__ float b2f(u16 u) {
    union { float f; unsigned int i; } v; v.i = ((unsigned int)u) << 16; return v.f;
}
__device__ __forceinline__ u16 f2b(float f) {
    union { float f; unsigned int i; } v; v.f = f;
    unsigned int x = v.i;
    return (u16)((x + 0x7fffu + ((x >> 16) & 1u)) >> 16);
}

// ------------------------------------------ K1a: 3-NN partial (256-pt chunks)
// grid (qchunk 32, schunk 8, b 8); per-chunk top-3 -> cand[(b*8192+n)*8+ck]
__global__ void knn_part_kernel(const float* __restrict__ xyz1, const float* __restrict__ xyz2,
                                float2* __restrict__ cand) {
    __shared__ float4 spt[256];
    int b = blockIdx.z, ck = blockIdx.y, tid = threadIdx.x;
    const float* p2 = xyz2 + (size_t)b * 3 * 2048;
    int s0 = ck << 8;
    {
        int s = s0 + tid;
        float x = p2[s], y = p2[2048 + s], z = p2[4096 + s];
        spt[tid] = make_float4(x, y, z, (x * x + y * y) + z * z);
    }
    __syncthreads();
    int n = blockIdx.x * 256 + tid;
    const float* p1 = xyz1 + (size_t)b * 3 * 8192;
    float qx = p1[n], qy = p1[8192 + n], qz = p1[16384 + n];
    float qn = (qx * qx + qy * qy) + qz * qz;
    float d0 = 3.4e38f, d1 = 3.4e38f, d2 = 3.4e38f;
    int i0 = 0, i1 = 0, i2 = 0;
#pragma unroll 4
    for (int s = 0; s < 256; ++s) {
        float4 p = spt[s];
        float dot = (qx * p.x + qy * p.y) + qz * p.z;
        float d = (-2.f * dot + qn) + p.w;   // reference op order
        if (d < d2) {
            int gi = s0 + s;
            if (d < d1) {
                if (d < d0) { d2 = d1; i2 = i1; d1 = d0; i1 = i0; d0 = d; i0 = gi; }
                else        { d2 = d1; i2 = i1; d1 = d;  i1 = gi; }
            } else          { d2 = d;  i2 = gi; }
        }
    }
    float2* c = cand + (((size_t)b * 8192 + n) * 8 + ck) * 3;
    c[0] = make_float2(d0, __int_as_float(i0));
    c[1] = make_float2(d1, __int_as_float(i1));
    c[2] = make_float2(d2, __int_as_float(i2));
}

// ------------------------------------------ K1b: merge 8x3 candidates
__global__ void knn_merge_kernel(const float2* __restrict__ cand,
                                 int* __restrict__ idx_out, float* __restrict__ w_out) {
    int t = blockIdx.x * 256 + threadIdx.x;    // b*8192+n
    const float2* c = cand + (size_t)t * 24;
    float d0 = 3.4e38f, d1 = 3.4e38f, d2 = 3.4e38f;
    int i0 = 0, i1 = 0, i2 = 0;
#pragma unroll
    for (int k = 0; k < 24; ++k) {
        float2 p = c[k];
        float d = p.x;
        if (d < d2) {
            int gi = __float_as_int(p.y);
            if (d < d1) {
                if (d < d0) { d2 = d1; i2 = i1; d1 = d0; i1 = i0; d0 = d; i0 = gi; }
                else        { d2 = d1; i2 = i1; d1 = d;  i1 = gi; }
            } else          { d2 = d;  i2 = gi; }
        }
    }
    float r0 = 1.f / (d0 + 1e-8f), r1 = 1.f / (d1 + 1e-8f), r2 = 1.f / (d2 + 1e-8f);
    float inv = 1.f / (r0 + r1 + r2);
    size_t base = (size_t)t * 3;
    idx_out[base] = i0; idx_out[base + 1] = i1; idx_out[base + 2] = i2;
    w_out[base] = r0 * inv; w_out[base + 1] = r1 * inv; w_out[base + 2] = r2 * inv;
}

// ------------------------------------------- K2: build X0^T [B][N][384] bf16
__global__ void build_x0_kernel(const float* __restrict__ points1, const float* __restrict__ points2,
                                const int* __restrict__ idx, const float* __restrict__ wgt,
                                u16* __restrict__ x0t) {
    __shared__ u16 tile[64][392];
    int b = blockIdx.y;
    int n0 = blockIdx.x * 64;
    int tid = threadIdx.x, lane = tid & 63, wv = tid >> 6;
    const float* p1 = points1 + (size_t)b * 128 * 8192;
    for (int c = wv; c < 128; c += 4)
        tile[lane][c] = f2b(p1[(size_t)c * 8192 + n0 + lane]);
    size_t ib = ((size_t)b * 8192 + n0 + lane) * 3;
    int j0 = idx[ib], j1 = idx[ib + 1], j2 = idx[ib + 2];
    float w0 = wgt[ib], w1 = wgt[ib + 1], w2 = wgt[ib + 2];
    const float* p2 = points2 + (size_t)b * 256 * 2048;
    for (int c = wv; c < 256; c += 4) {
        const float* row = p2 + (size_t)c * 2048;
        float v = w0 * row[j0] + w1 * row[j1] + w2 * row[j2];
        tile[lane][128 + c] = f2b(v);
    }
    __syncthreads();
    for (int q = tid; q < 64 * 48; q += 256) {
        int r = q / 48, c8 = q % 48;
        uint4 vv = *(const uint4*)&tile[r][c8 * 8];
        *(uint4*)&x0t[((size_t)b * 8192 + n0 + r) * 384 + c8 * 8] = vv;
    }
}

// --------------------------------------------- weight f32 -> bf16 converter
__global__ void cvt_kernel(const float* __restrict__ src, u16* __restrict__ dst, int n) {
    int i = blockIdx.x * 256 + threadIdx.x;
    if (i < n) dst[i] = f2b(src[i]);
}

// ------------------------------------- K5: FiLM params
__global__ void film_kernel(const float* __restrict__ t_emb, const float* __restrict__ c_emb,
                            const float* __restrict__ tw, const float* __restrict__ tb,
                            const float* __restrict__ cw, const float* __restrict__ cb,
                            float* __restrict__ film) {
    __shared__ float te[256], ce[256];
    int b = blockIdx.x, tid = threadIdx.x;
    te[tid] = t_emb[b * 256 + tid];
    ce[tid] = c_emb[b * 256 + tid];
    __syncthreads();
    int j = tid + blockIdx.y * 256;
    const float* twr = tw + (size_t)j * 256;
    const float* cwr = cw + (size_t)j * 256;
    float s = 0.f;
    for (int k = 0; k < 256; ++k) s += te[k] * twr[k] + ce[k] * cwr[k];
    s += tb[j] + cb[j];
    film[b * 512 + j] = s;
}

// ------------------------------------------------- K3: GEMM (channel-last)
__global__ __launch_bounds__(256) void gemm_kernel(
        const u16* __restrict__ At, const u16* __restrict__ W, const float* __restrict__ bias,
        u16* __restrict__ Out, float* __restrict__ part,
        int K, int M, int gshift) {
    __shared__ u16 lA[128 * 64];
    __shared__ u16 lB[128 * 64];
    __shared__ float bpart[4][2];
    int b = blockIdx.z;
    int n0 = blockIdx.x * 128, o0 = blockIdx.y * 128;
    int tid = threadIdx.x, lane = tid & 63, wv = tid >> 6;
    int wn = wv & 1, wo = wv >> 1;
    if (tid < 8) ((float*)bpart)[tid] = 0.f;
    f32x4 acc[4][4];
#pragma unroll
    for (int i = 0; i < 4; i++)
#pragma unroll
        for (int j = 0; j < 4; j++) acc[i][j] = (f32x4){0.f, 0.f, 0.f, 0.f};

    const u16* aRow = At + ((size_t)b * 8192 + n0) * K;
    const u16* wRow = W + (size_t)o0 * K;
    int rl = lane >> 3;
    int csw = ((lane & 7) ^ rl) * 8;
    int nK = K >> 6;
    for (int kt = 0; kt < nK; ++kt) {
        int c0 = kt << 6;
#pragma unroll
        for (int p4 = 0; p4 < 4; p4++) {
            int p = wv * 4 + p4;
            GLOAD16(aRow + (size_t)(p * 8 + rl) * K + c0 + csw, &lA[p * 512]);
            GLOAD16(wRow + (size_t)(p * 8 + rl) * K + c0 + csw, &lB[p * 512]);
        }
        __syncthreads();
#pragma unroll
        for (int kk = 0; kk < 2; kk++) {
            bf16x8 af[4], bfr[4];
#pragma unroll
            for (int mf = 0; mf < 4; mf++) {
                int R = wn * 64 + mf * 16 + (lane & 15);
                af[mf] = *(const bf16x8*)&lA[R * 64 + ((kk * 4 + (lane >> 4)) ^ (R & 7)) * 8];
            }
#pragma unroll
            for (int nf = 0; nf < 4; nf++) {
                int R = wo * 64 + nf * 16 + (lane & 15);
                bfr[nf] = *(const bf16x8*)&lB[R * 64 + ((kk * 4 + (lane >> 4)) ^ (R & 7)) * 8];
            }
#pragma unroll
            for (int mf = 0; mf < 4; mf++)
#pragma unroll
                for (int nf = 0; nf < 4; nf++)
                    acc[mf][nf] = __builtin_amdgcn_mfma_f32_16x16x32_bf16(af[mf], bfr[nf], acc[mf][nf], 0, 0, 0);
        }
        __syncthreads();
    }
#pragma unroll
    for (int nf = 0; nf < 4; nf++) {
        int od = wo * 64 + nf * 16;
        float bv = bias[o0 + od + (lane & 15)];
        float s1 = 0.f, s2 = 0.f;
#pragma unroll
        for (int mf = 0; mf < 4; mf++)
#pragma unroll
            for (int r = 0; r < 4; r++) {
                float v = acc[mf][nf][r] + bv;
                acc[mf][nf][r] = v;
                s1 += v; s2 += v * v;
            }
#pragma unroll
        for (int off = 32; off > 0; off >>= 1) {
            s1 += __shfl_xor(s1, off, 64);
            s2 += __shfl_xor(s2, off, 64);
        }
        if (lane == 0) {
            int gl = od >> gshift;
            atomicAdd(&bpart[gl][0], s1);
            atomicAdd(&bpart[gl][1], s2);
        }
    }
#pragma unroll
    for (int mf = 0; mf < 4; mf++) {
        int nbase = n0 + wn * 64 + mf * 16 + (lane >> 4) * 4;
#pragma unroll
        for (int r = 0; r < 4; r++) {
            size_t rowoff = ((size_t)b * 8192 + nbase + r) * M + o0 + wo * 64 + (lane & 15);
#pragma unroll
            for (int nf = 0; nf < 4; nf++)
                Out[rowoff + nf * 16] = f2b(acc[mf][nf][r]);
        }
    }
    __syncthreads();
    int nlg = 128 >> gshift;
    if (tid < 2 * nlg) {
        int gl = tid >> 1, s = tid & 1;
        int g = (o0 >> gshift) + gl;
        part[(((size_t)b * 8 + g) * 2 + s) * 64 + blockIdx.x] = bpart[gl][s];
    }
}

// ------------------------------------- K3b: reduce partials -> stats[128]
__global__ void gn_reduce_kernel(const float* __restrict__ part, float* __restrict__ stats) {
    int t = threadIdx.x;
    const float4* p = (const float4*)(part + (size_t)t * 64);
    float s = 0.f;
#pragma unroll
    for (int i = 0; i < 16; i++) { float4 v = p[i]; s += (v.x + v.y) + (v.z + v.w); }
    stats[t] = s;
}

// ------------------- K4: in-place GroupNorm + SiLU, fixed-channel threads
__global__ void gn_act2_kernel(u16* __restrict__ Y, const float* __restrict__ gw,
                               const float* __restrict__ gb, const float* __restrict__ stats,
                               int c8bits, int gshift, float invCnt) {
    int t = blockIdx.x * 256 + threadIdx.x;
    int C8m = (1 << c8bits) - 1;
    int c8 = t & C8m;
    int c0 = c8 << 3;
    int g = c0 >> gshift;
    int row0 = t >> c8bits;
    int rowstep = (gridDim.x * 256) >> c8bits;
    float4 w0 = *(const float4*)(gw + c0), w1 = *(const float4*)(gw + c0 + 4);
    float4 b0 = *(const float4*)(gb + c0), b1 = *(const float4*)(gb + c0 + 4);
    float wv[8] = {w0.x, w0.y, w0.z, w0.w, w1.x, w1.y, w1.z, w1.w};
    float bv[8] = {b0.x, b0.y, b0.z, b0.w, b1.x, b1.y, b1.z, b1.w};
    float A[8], Bc[8];
    int bprev = -1;
    for (int row = row0; row < 65536; row += rowstep) {
        int b = row >> 13;           // wave-uniform
        if (b != bprev) {
            bprev = b;
            float sum = stats[(b * 8 + g) * 2], ssq = stats[(b * 8 + g) * 2 + 1];
            float m = sum * invCnt;
            float rstd = rsqrtf(fmaxf(ssq * invCnt - m * m, 0.f) + 1e-5f);
#pragma unroll
            for (int j = 0; j < 8; j++) { A[j] = rstd * wv[j]; Bc[j] = bv[j] - m * rstd * wv[j]; }
        }
        u16* p = Y + (((size_t)row << c8bits) << 3) + c0;
        uint4 v4 = *(const uint4*)p;
        u16* vu = (u16*)&v4;
#pragma unroll
        for (int j = 0; j < 8; j++) {
            float v = b2f(vu[j]) * A[j] + Bc[j];
            v = v * __builtin_amdgcn_rcpf(1.f + __expf(-v));   // silu
            vu[j] = f2b(v);
        }
        *(uint4*)p = v4;
    }
}

// ----------------------- K6: GN2 + FiLM + residual, transpose to [B][C][N] f32
__global__ void final_kernel(const u16* __restrict__ Y2, const u16* __restrict__ X,
                             const float* __restrict__ g2w, const float* __restrict__ g2b,
                             const float* __restrict__ stats, const float* __restrict__ film,
                             float* __restrict__ out) {
    __shared__ float tile[64][257];
    int b = blockIdx.y, n0 = blockIdx.x * 64, tid = threadIdx.x;
    const float invCnt = 1.f / (32.f * 8192.f);
    int c8 = tid & 31, c0 = c8 << 3, g = c8 >> 2;
    float sum = stats[(b * 8 + g) * 2], ssq = stats[(b * 8 + g) * 2 + 1];
    float m = sum * invCnt, rstd = rsqrtf(fmaxf(ssq * invCnt - m * m, 0.f) + 1e-5f);
    float4 w0 = *(const float4*)(g2w + c0), w1 = *(const float4*)(g2w + c0 + 4);
    float4 q0 = *(const float4*)(g2b + c0), q1 = *(const float4*)(g2b + c0 + 4);
    float4 f0 = *(const float4*)(film + b * 512 + c0), f1 = *(const float4*)(film + b * 512 + c0 + 4);
    float4 h0 = *(const float4*)(film + b * 512 + 256 + c0), h1 = *(const float4*)(film + b * 512 + 256 + c0 + 4);
    float wv[8] = {w0.x, w0.y, w0.z, w0.w, w1.x, w1.y, w1.z, w1.w};
    float qv[8] = {q0.x, q0.y, q0.z, q0.w, q1.x, q1.y, q1.z, q1.w};
    float fs[8] = {f0.x, f0.y, f0.z, f0.w, f1.x, f1.y, f1.z, f1.w};
    float fh[8] = {h0.x, h0.y, h0.z, h0.w, h1.x, h1.y, h1.z, h1.w};
    float A[8], Bc[8];
#pragma unroll
    for (int j = 0; j < 8; j++) {
        float sc = 1.f + fs[j];
        A[j] = rstd * wv[j] * sc;
        Bc[j] = (qv[j] - m * rstd * wv[j]) * sc + fh[j];
    }
    int nrb = tid >> 5;
#pragma unroll
    for (int k = 0; k < 8; k++) {
        int nr = nrb + k * 8;
        size_t base = ((size_t)b * 8192 + n0 + nr) * 256 + c0;
        uint4 yv = *(const uint4*)(Y2 + base);
        uint4 xv = *(const uint4*)(X + base);
        const u16* yy = (const u16*)&yv;
        const u16* xx = (const u16*)&xv;
#pragma unroll
        for (int j = 0; j < 8; j++)
            tile[nr][c0 + j] = b2f(yy[j]) * A[j] + Bc[j] + b2f(xx[j]);
    }
    __syncthreads();
    for (int q = tid; q < 256 * 16; q += 256) {
        int c = q >> 4, n4 = q & 15;
        float4 o;
        o.x = tile[n4 * 4 + 0][c];
        o.y = tile[n4 * 4 + 1][c];
        o.z = tile[n4 * 4 + 2][c];
        o.w = tile[n4 * 4 + 3][c];
        *(float4*)&out[((size_t)b * 256 + c) * 8192 + n0 + n4 * 4] = o;
    }
}

// ---------------------------------------------------------------------------
extern "C" void kernel_launch(void* const* d_in, const int* in_sizes, int n_in,
                              void* d_out, int out_size, void* d_ws, size_t ws_size,
                              hipStream_t stream) {
    const float* xyz1    = (const float*)d_in[0];
    const float* points1 = (const float*)d_in[1];
    const float* xyz2    = (const float*)d_in[2];
    const float* points2 = (const float*)d_in[3];
    const float* t_emb   = (const float*)d_in[4];
    const float* c_emb   = (const float*)d_in[5];
    const float* mlp_w   = (const float*)d_in[6];
    const float* mlp_b   = (const float*)d_in[7];
    const float* mlp_gw  = (const float*)d_in[8];
    const float* mlp_gb  = (const float*)d_in[9];
    const float* c1w     = (const float*)d_in[10];
    const float* c1b     = (const float*)d_in[11];
    const float* g1w     = (const float*)d_in[12];
    const float* g1b     = (const float*)d_in[13];
    const float* c2w     = (const float*)d_in[14];
    const float* c2b     = (const float*)d_in[15];
    const float* g2w     = (const float*)d_in[16];
    const float* g2b     = (const float*)d_in[17];
    const float* tw      = (const float*)d_in[18];
    const float* tb      = (const float*)d_in[19];
    const float* cw      = (const float*)d_in[20];
    const float* cb      = (const float*)d_in[21];

    char* ws = (char*)d_ws;
    int*   idx    = (int*)ws;
    float* wgt    = (float*)(ws + 786432);
    float* stats0 = (float*)(ws + 1572864);
    float* stats1 = (float*)(ws + 1573376);
    float* stats2 = (float*)(ws + 1573888);
    float* film   = (float*)(ws + 1574400);
    float* part0  = (float*)(ws + 1590784);
    float* part1  = (float*)(ws + 1623552);
    float* part2  = (float*)(ws + 1656320);
    u16* wb_mlp   = (u16*)(ws + 1689088);
    u16* wb_c1    = (u16*)(ws + 1885696);
    u16* wb_c2    = (u16*)(ws + 2409984);
    u16* X0t = (u16*)(ws + 4194304);               //  50,331,648 B [B][N][384]
    u16* Y1t = (u16*)(ws + 54525952);              //  33,554,432 B [B][N][256]
    u16* H1t = (u16*)(ws + 88080384);              // 134,217,728 B [B][N][1024]
    u16* Y2t = X0t;
    float2* cand = (float2*)X0t;   // 12.6 MB, dead before build_x0 writes X0t
    float* out = (float*)d_out;

    cvt_kernel<<<384, 256, 0, stream>>>(mlp_w, wb_mlp, 98304);
    cvt_kernel<<<1024, 256, 0, stream>>>(c1w, wb_c1, 262144);
    cvt_kernel<<<1024, 256, 0, stream>>>(c2w, wb_c2, 262144);
    knn_part_kernel<<<dim3(32, 8, 8), 256, 0, stream>>>(xyz1, xyz2, cand);
    knn_merge_kernel<<<256, 256, 0, stream>>>(cand, idx, wgt);
    build_x0_kernel<<<dim3(128, 8), 256, 0, stream>>>(points1, points2, idx, wgt, X0t);
    film_kernel<<<dim3(8, 2), 256, 0, stream>>>(t_emb, c_emb, tw, tb, cw, cb, film);
    // stage 1: conv(384->256) + GN(gs=32) + SiLU  -> identity X
    gemm_kernel<<<dim3(64, 2, 8), 256, 0, stream>>>(X0t, wb_mlp, mlp_b, Y1t, part0, 384, 256, 5);
    gn_reduce_kernel<<<1, 128, 0, stream>>>(part0, stats0);
    gn_act2_kernel<<<512, 256, 0, stream>>>(Y1t, mlp_gw, mlp_gb, stats0, 5, 5, 1.f / (32.f * 8192.f));
    // stage 2: conv(256->1024) + GN(gs=128) + SiLU
    gemm_kernel<<<dim3(64, 8, 8), 256, 0, stream>>>(Y1t, wb_c1, c1b, H1t, part1, 256, 1024, 7);
    gn_reduce_kernel<<<1, 128, 0, stream>>>(part1, stats1);
    gn_act2_kernel<<<2048, 256, 0, stream>>>(H1t, g1w, g1b, stats1, 7, 7, 1.f / (128.f * 8192.f));
    // stage 3: conv(1024->256); GN2 + FiLM + residual fused into final
    gemm_kernel<<<dim3(64, 2, 8), 256, 0, stream>>>(H1t, wb_c2, c2b, Y2t, part2, 1024, 256, 5);
    gn_reduce_kernel<<<1, 128, 0, stream>>>(part2, stats2);
    final_kernel<<<dim3(128, 8), 256, 0, stream>>>(Y2t, Y1t, g2w, g2b, stats2, film, out);
}

// Round 6
// 383.970 us; speedup vs baseline: 4.7190x; 1.1419x over previous
//
#include <hip/hip_runtime.h>
#include <hip/hip_bf16.h>

typedef unsigned short u16;
typedef __attribute__((ext_vector_type(4))) float f32x4;
typedef __attribute__((ext_vector_type(8))) short bf16x8;

typedef const __attribute__((address_space(1))) void GV;
typedef __attribute__((address_space(3))) void LV;
#define GLOAD16(g, l) __builtin_amdgcn_global_load_lds((GV*)(g), (LV*)(l), 16, 0, 0)

__device__ __forceinline__ float b2f(u16 u) {
    union { float f; unsigned int i; } v; v.i = ((unsigned int)u) << 16; return v.f;
}
__device__ __forceinline__ u16 f2b(float f) {
    union { float f; unsigned int i; } v; v.f = f;
    unsigned int x = v.i;
    return (u16)((x + 0x7fffu + ((x >> 16) & 1u)) >> 16);
}

// ------------------------------------------ K1a: 3-NN partial (256-pt chunks)
__global__ void knn_part_kernel(const float* __restrict__ xyz1, const float* __restrict__ xyz2,
                                float2* __restrict__ cand) {
    __shared__ float4 spt[256];
    int b = blockIdx.z, ck = blockIdx.y, tid = threadIdx.x;
    const float* p2 = xyz2 + (size_t)b * 3 * 2048;
    int s0 = ck << 8;
    {
        int s = s0 + tid;
        float x = p2[s], y = p2[2048 + s], z = p2[4096 + s];
        spt[tid] = make_float4(x, y, z, (x * x + y * y) + z * z);
    }
    __syncthreads();
    int n = blockIdx.x * 256 + tid;
    const float* p1 = xyz1 + (size_t)b * 3 * 8192;
    float qx = p1[n], qy = p1[8192 + n], qz = p1[16384 + n];
    float qn = (qx * qx + qy * qy) + qz * qz;
    float d0 = 3.4e38f, d1 = 3.4e38f, d2 = 3.4e38f;
    int i0 = 0, i1 = 0, i2 = 0;
#pragma unroll 4
    for (int s = 0; s < 256; ++s) {
        float4 p = spt[s];
        float dot = (qx * p.x + qy * p.y) + qz * p.z;
        float d = (-2.f * dot + qn) + p.w;   // reference op order
        if (d < d2) {
            int gi = s0 + s;
            if (d < d1) {
                if (d < d0) { d2 = d1; i2 = i1; d1 = d0; i1 = i0; d0 = d; i0 = gi; }
                else        { d2 = d1; i2 = i1; d1 = d;  i1 = gi; }
            } else          { d2 = d;  i2 = gi; }
        }
    }
    float2* c = cand + (((size_t)b * 8192 + n) * 8 + ck) * 3;
    c[0] = make_float2(d0, __int_as_float(i0));
    c[1] = make_float2(d1, __int_as_float(i1));
    c[2] = make_float2(d2, __int_as_float(i2));
}

// ------------------------------------------ K1b: merge 8x3 candidates
__global__ void knn_merge_kernel(const float2* __restrict__ cand,
                                 int* __restrict__ idx_out, float* __restrict__ w_out) {
    int t = blockIdx.x * 256 + threadIdx.x;
    const float2* c = cand + (size_t)t * 24;
    float d0 = 3.4e38f, d1 = 3.4e38f, d2 = 3.4e38f;
    int i0 = 0, i1 = 0, i2 = 0;
#pragma unroll
    for (int k = 0; k < 24; ++k) {
        float2 p = c[k];
        float d = p.x;
        if (d < d2) {
            int gi = __float_as_int(p.y);
            if (d < d1) {
                if (d < d0) { d2 = d1; i2 = i1; d1 = d0; i1 = i0; d0 = d; i0 = gi; }
                else        { d2 = d1; i2 = i1; d1 = d;  i1 = gi; }
            } else          { d2 = d;  i2 = gi; }
        }
    }
    float r0 = 1.f / (d0 + 1e-8f), r1 = 1.f / (d1 + 1e-8f), r2 = 1.f / (d2 + 1e-8f);
    float inv = 1.f / (r0 + r1 + r2);
    size_t base = (size_t)t * 3;
    idx_out[base] = i0; idx_out[base + 1] = i1; idx_out[base + 2] = i2;
    w_out[base] = r0 * inv; w_out[base + 1] = r1 * inv; w_out[base + 2] = r2 * inv;
}

// ---------------------- K2a: per-batch transpose f32 [C][S] -> bf16 [S][C]
// LDS tile row stride 70 u16 = 35 words (odd) -> conflict-free both phases.
__global__ void tr_kernel(const float* __restrict__ src, u16* __restrict__ dst, int C, int S) {
    __shared__ u16 tile[64][70];
    int b = blockIdx.z;
    int s0 = blockIdx.x * 64, c0 = blockIdx.y * 64;
    int tid = threadIdx.x, lane = tid & 63, wv = tid >> 6;
    const float* sp = src + ((size_t)b * C + c0) * S + s0;
    for (int c = wv; c < 64; c += 4)
        tile[lane][c] = f2b(sp[(size_t)c * S + lane]);
    __syncthreads();
    u16* dp = dst + ((size_t)b * S + s0) * C + c0;
    int s = tid >> 5, cp = tid & 31;
#pragma unroll
    for (int k = 0; k < 8; ++k) {
        int r = s + k * 8;
        unsigned int v = *(const unsigned int*)&tile[r][cp * 2];
        *(unsigned int*)&dp[(size_t)r * C + cp * 2] = v;
    }
}

// ---------------- K2b: build X0^T [B][N][384]; quad-per-point, fully coalesced
__global__ void build_x0_kernel(const u16* __restrict__ p1t, const u16* __restrict__ p2t,
                                const int* __restrict__ idx, const float* __restrict__ wgt,
                                u16* __restrict__ x0t) {
    int b = blockIdx.y;
    int n = blockIdx.x * 64 + (threadIdx.x >> 2);
    int q = threadIdx.x & 3;
    size_t ib = ((size_t)b * 8192 + n) * 3;
    int j0 = idx[ib], j1 = idx[ib + 1], j2 = idx[ib + 2];
    float w0 = wgt[ib], w1 = wgt[ib + 1], w2 = wgt[ib + 2];
    const u16* pr = p1t + ((size_t)b * 8192 + n) * 128;
    const u16* r0 = p2t + ((size_t)b * 2048 + j0) * 256;
    const u16* r1 = p2t + ((size_t)b * 2048 + j1) * 256;
    const u16* r2 = p2t + ((size_t)b * 2048 + j2) * 256;
    u16* out = x0t + ((size_t)b * 8192 + n) * 384;
#pragma unroll
    for (int i = 0; i < 4; ++i) {       // points1 copy: lanes of a quad read consecutive 16B
        int ch = (i * 4 + q) * 8;
        *(uint4*)&out[ch] = *(const uint4*)&pr[ch];
    }
#pragma unroll
    for (int i = 0; i < 8; ++i) {       // interp: per instr each point touches ONE 64B line/row
        int c = (i * 4 + q) * 8;
        bf16x8 a0 = *(const bf16x8*)&r0[c];
        bf16x8 a1 = *(const bf16x8*)&r1[c];
        bf16x8 a2 = *(const bf16x8*)&r2[c];
        u16 ovu[8] __attribute__((aligned(16)));
#pragma unroll
        for (int j = 0; j < 8; ++j) {
            float v = w0 * b2f((u16)a0[j]) + w1 * b2f((u16)a1[j]) + w2 * b2f((u16)a2[j]);
            ovu[j] = f2b(v);
        }
        *(uint4*)&out[128 + c] = *(const uint4*)ovu;
    }
}

// --------------------------------------------- weight f32 -> bf16 converter
__global__ void cvt_kernel(const float* __restrict__ src, u16* __restrict__ dst, int n) {
    int i = blockIdx.x * 256 + threadIdx.x;
    if (i < n) dst[i] = f2b(src[i]);
}

// ------------------------------------- K5: FiLM params
__global__ void film_kernel(const float* __restrict__ t_emb, const float* __restrict__ c_emb,
                            const float* __restrict__ tw, const float* __restrict__ tb,
                            const float* __restrict__ cw, const float* __restrict__ cb,
                            float* __restrict__ film) {
    __shared__ float te[256], ce[256];
    int b = blockIdx.x, tid = threadIdx.x;
    te[tid] = t_emb[b * 256 + tid];
    ce[tid] = c_emb[b * 256 + tid];
    __syncthreads();
    int j = tid + blockIdx.y * 256;
    const float* twr = tw + (size_t)j * 256;
    const float* cwr = cw + (size_t)j * 256;
    float s = 0.f;
    for (int k = 0; k < 256; ++k) s += te[k] * twr[k] + ce[k] * cwr[k];
    s += tb[j] + cb[j];
    film[b * 512 + j] = s;
}

// ------------------------------------------------- K3: GEMM (channel-last)
__global__ __launch_bounds__(256) void gemm_kernel(
        const u16* __restrict__ At, const u16* __restrict__ W, const float* __restrict__ bias,
        u16* __restrict__ Out, float* __restrict__ part,
        int K, int M, int gshift) {
    __shared__ u16 lA[128 * 64];
    __shared__ u16 lB[128 * 64];
    __shared__ float bpart[4][2];
    int b = blockIdx.z;
    int n0 = blockIdx.x * 128, o0 = blockIdx.y * 128;
    int tid = threadIdx.x, lane = tid & 63, wv = tid >> 6;
    int wn = wv & 1, wo = wv >> 1;
    if (tid < 8) ((float*)bpart)[tid] = 0.f;
    f32x4 acc[4][4];
#pragma unroll
    for (int i = 0; i < 4; i++)
#pragma unroll
        for (int j = 0; j < 4; j++) acc[i][j] = (f32x4){0.f, 0.f, 0.f, 0.f};

    const u16* aRow = At + ((size_t)b * 8192 + n0) * K;
    const u16* wRow = W + (size_t)o0 * K;
    int rl = lane >> 3;
    int csw = ((lane & 7) ^ rl) * 8;
    int nK = K >> 6;
    for (int kt = 0; kt < nK; ++kt) {
        int c0 = kt << 6;
#pragma unroll
        for (int p4 = 0; p4 < 4; p4++) {
            int p = wv * 4 + p4;
            GLOAD16(aRow + (size_t)(p * 8 + rl) * K + c0 + csw, &lA[p * 512]);
            GLOAD16(wRow + (size_t)(p * 8 + rl) * K + c0 + csw, &lB[p * 512]);
        }
        __syncthreads();
#pragma unroll
        for (int kk = 0; kk < 2; kk++) {
            bf16x8 af[4], bfr[4];
#pragma unroll
            for (int mf = 0; mf < 4; mf++) {
                int R = wn * 64 + mf * 16 + (lane & 15);
                af[mf] = *(const bf16x8*)&lA[R * 64 + ((kk * 4 + (lane >> 4)) ^ (R & 7)) * 8];
            }
#pragma unroll
            for (int nf = 0; nf < 4; nf++) {
                int R = wo * 64 + nf * 16 + (lane & 15);
                bfr[nf] = *(const bf16x8*)&lB[R * 64 + ((kk * 4 + (lane >> 4)) ^ (R & 7)) * 8];
            }
#pragma unroll
            for (int mf = 0; mf < 4; mf++)
#pragma unroll
                for (int nf = 0; nf < 4; nf++)
                    acc[mf][nf] = __builtin_amdgcn_mfma_f32_16x16x32_bf16(af[mf], bfr[nf], acc[mf][nf], 0, 0, 0);
        }
        __syncthreads();
    }
#pragma unroll
    for (int nf = 0; nf < 4; nf++) {
        int od = wo * 64 + nf * 16;
        float bv = bias[o0 + od + (lane & 15)];
        float s1 = 0.f, s2 = 0.f;
#pragma unroll
        for (int mf = 0; mf < 4; mf++)
#pragma unroll
            for (int r = 0; r < 4; r++) {
                float v = acc[mf][nf][r] + bv;
                acc[mf][nf][r] = v;
                s1 += v; s2 += v * v;
            }
#pragma unroll
        for (int off = 32; off > 0; off >>= 1) {
            s1 += __shfl_xor(s1, off, 64);
            s2 += __shfl_xor(s2, off, 64);
        }
        if (lane == 0) {
            int gl = od >> gshift;
            atomicAdd(&bpart[gl][0], s1);
            atomicAdd(&bpart[gl][1], s2);
        }
    }
#pragma unroll
    for (int mf = 0; mf < 4; mf++) {
        int nbase = n0 + wn * 64 + mf * 16 + (lane >> 4) * 4;
#pragma unroll
        for (int r = 0; r < 4; r++) {
            size_t rowoff = ((size_t)b * 8192 + nbase + r) * M + o0 + wo * 64 + (lane & 15);
#pragma unroll
            for (int nf = 0; nf < 4; nf++)
                Out[rowoff + nf * 16] = f2b(acc[mf][nf][r]);
        }
    }
    __syncthreads();
    int nlg = 128 >> gshift;
    if (tid < 2 * nlg) {
        int gl = tid >> 1, s = tid & 1;
        int g = (o0 >> gshift) + gl;
        part[(((size_t)b * 8 + g) * 2 + s) * 64 + blockIdx.x] = bpart[gl][s];
    }
}

// ------------------------------------- K3b: reduce partials -> stats[128]
__global__ void gn_reduce_kernel(const float* __restrict__ part, float* __restrict__ stats) {
    int t = threadIdx.x;
    const float4* p = (const float4*)(part + (size_t)t * 64);
    float s = 0.f;
#pragma unroll
    for (int i = 0; i < 16; i++) { float4 v = p[i]; s += (v.x + v.y) + (v.z + v.w); }
    stats[t] = s;
}

// ------------------- K4: in-place GroupNorm + SiLU, fixed-channel threads
__global__ void gn_act2_kernel(u16* __restrict__ Y, const float* __restrict__ gw,
                               const float* __restrict__ gb, const float* __restrict__ stats,
                               int c8bits, int gshift, float invCnt) {
    int t = blockIdx.x * 256 + threadIdx.x;
    int C8m = (1 << c8bits) - 1;
    int c8 = t & C8m;
    int c0 = c8 << 3;
    int g = c0 >> gshift;
    int row0 = t >> c8bits;
    int rowstep = (gridDim.x * 256) >> c8bits;
    float4 w0 = *(const float4*)(gw + c0), w1 = *(const float4*)(gw + c0 + 4);
    float4 b0 = *(const float4*)(gb + c0), b1 = *(const float4*)(gb + c0 + 4);
    float wv[8] = {w0.x, w0.y, w0.z, w0.w, w1.x, w1.y, w1.z, w1.w};
    float bv[8] = {b0.x, b0.y, b0.z, b0.w, b1.x, b1.y, b1.z, b1.w};
    float A[8], Bc[8];
    int bprev = -1;
    for (int row = row0; row < 65536; row += rowstep) {
        int b = row >> 13;
        if (b != bprev) {
            bprev = b;
            float sum = stats[(b * 8 + g) * 2], ssq = stats[(b * 8 + g) * 2 + 1];
            float m = sum * invCnt;
            float rstd = rsqrtf(fmaxf(ssq * invCnt - m * m, 0.f) + 1e-5f);
#pragma unroll
            for (int j = 0; j < 8; j++) { A[j] = rstd * wv[j]; Bc[j] = bv[j] - m * rstd * wv[j]; }
        }
        u16* p = Y + (((size_t)row << c8bits) << 3) + c0;
        uint4 v4 = *(const uint4*)p;
        u16* vu = (u16*)&v4;
#pragma unroll
        for (int j = 0; j < 8; j++) {
            float v = b2f(vu[j]) * A[j] + Bc[j];
            v = v * __builtin_amdgcn_rcpf(1.f + __expf(-v));   // silu
            vu[j] = f2b(v);
        }
        *(uint4*)p = v4;
    }
}

// ----------------------- K6: GN2 + FiLM + residual, transpose to [B][C][N] f32
__global__ void final_kernel(const u16* __restrict__ Y2, const u16* __restrict__ X,
                             const float* __restrict__ g2w, const float* __restrict__ g2b,
                             const float* __restrict__ stats, const float* __restrict__ film,
                             float* __restrict__ out) {
    __shared__ float tile[64][257];
    int b = blockIdx.y, n0 = blockIdx.x * 64, tid = threadIdx.x;
    const float invCnt = 1.f / (32.f * 8192.f);
    int c8 = tid & 31, c0 = c8 << 3, g = c8 >> 2;
    float sum = stats[(b * 8 + g) * 2], ssq = stats[(b * 8 + g) * 2 + 1];
    float m = sum * invCnt, rstd = rsqrtf(fmaxf(ssq * invCnt - m * m, 0.f) + 1e-5f);
    float4 w0 = *(const float4*)(g2w + c0), w1 = *(const float4*)(g2w + c0 + 4);
    float4 q0 = *(const float4*)(g2b + c0), q1 = *(const float4*)(g2b + c0 + 4);
    float4 f0 = *(const float4*)(film + b * 512 + c0), f1 = *(const float4*)(film + b * 512 + c0 + 4);
    float4 h0 = *(const float4*)(film + b * 512 + 256 + c0), h1 = *(const float4*)(film + b * 512 + 256 + c0 + 4);
    float wv[8] = {w0.x, w0.y, w0.z, w0.w, w1.x, w1.y, w1.z, w1.w};
    float qv[8] = {q0.x, q0.y, q0.z, q0.w, q1.x, q1.y, q1.z, q1.w};
    float fs[8] = {f0.x, f0.y, f0.z, f0.w, f1.x, f1.y, f1.z, f1.w};
    float fh[8] = {h0.x, h0.y, h0.z, h0.w, h1.x, h1.y, h1.z, h1.w};
    float A[8], Bc[8];
#pragma unroll
    for (int j = 0; j < 8; j++) {
        float sc = 1.f + fs[j];
        A[j] = rstd * wv[j] * sc;
        Bc[j] = (qv[j] - m * rstd * wv[j]) * sc + fh[j];
    }
    int nrb = tid >> 5;
#pragma unroll
    for (int k = 0; k < 8; k++) {
        int nr = nrb + k * 8;
        size_t base = ((size_t)b * 8192 + n0 + nr) * 256 + c0;
        uint4 yv = *(const uint4*)(Y2 + base);
        uint4 xv = *(const uint4*)(X + base);
        const u16* yy = (const u16*)&yv;
        const u16* xx = (const u16*)&xv;
#pragma unroll
        for (int j = 0; j < 8; j++)
            tile[nr][c0 + j] = b2f(yy[j]) * A[j] + Bc[j] + b2f(xx[j]);
    }
    __syncthreads();
    for (int q = tid; q < 256 * 16; q += 256) {
        int c = q >> 4, n4 = q & 15;
        float4 o;
        o.x = tile[n4 * 4 + 0][c];
        o.y = tile[n4 * 4 + 1][c];
        o.z = tile[n4 * 4 + 2][c];
        o.w = tile[n4 * 4 + 3][c];
        *(float4*)&out[((size_t)b * 256 + c) * 8192 + n0 + n4 * 4] = o;
    }
}

// ---------------------------------------------------------------------------
extern "C" void kernel_launch(void* const* d_in, const int* in_sizes, int n_in,
                              void* d_out, int out_size, void* d_ws, size_t ws_size,
                              hipStream_t stream) {
    const float* xyz1    = (const float*)d_in[0];
    const float* points1 = (const float*)d_in[1];
    const float* xyz2    = (const float*)d_in[2];
    const float* points2 = (const float*)d_in[3];
    const float* t_emb   = (const float*)d_in[4];
    const float* c_emb   = (const float*)d_in[5];
    const float* mlp_w   = (const float*)d_in[6];
    const float* mlp_b   = (const float*)d_in[7];
    const float* mlp_gw  = (const float*)d_in[8];
    const float* mlp_gb  = (const float*)d_in[9];
    const float* c1w     = (const float*)d_in[10];
    const float* c1b     = (const float*)d_in[11];
    const float* g1w     = (const float*)d_in[12];
    const float* g1b     = (const float*)d_in[13];
    const float* c2w     = (const float*)d_in[14];
    const float* c2b     = (const float*)d_in[15];
    const float* g2w     = (const float*)d_in[16];
    const float* g2b     = (const float*)d_in[17];
    const float* tw      = (const float*)d_in[18];
    const float* tb      = (const float*)d_in[19];
    const float* cw      = (const float*)d_in[20];
    const float* cb      = (const float*)d_in[21];

    char* ws = (char*)d_ws;
    int*   idx    = (int*)ws;
    float* wgt    = (float*)(ws + 786432);
    float* stats0 = (float*)(ws + 1572864);
    float* stats1 = (float*)(ws + 1573376);
    float* stats2 = (float*)(ws + 1573888);
    float* film   = (float*)(ws + 1574400);
    float* part0  = (float*)(ws + 1590784);
    float* part1  = (float*)(ws + 1623552);
    float* part2  = (float*)(ws + 1656320);
    u16* wb_mlp   = (u16*)(ws + 1689088);
    u16* wb_c1    = (u16*)(ws + 1885696);
    u16* wb_c2    = (u16*)(ws + 2409984);
    u16* X0t = (u16*)(ws + 4194304);               //  50,331,648 B [B][N][384]
    u16* Y1t = (u16*)(ws + 54525952);              //  33,554,432 B [B][N][256]
    u16* H1t = (u16*)(ws + 88080384);              // 134,217,728 B [B][N][1024]
    u16* Y2t = X0t;
    float2* cand = (float2*)X0t;   // 12.6 MB, dead before build_x0 writes X0t
    u16* p1t = H1t;                        // 16.8 MB, dead before GEMM2 writes H1t
    u16* p2t = H1t + 8388608ull;           //  8.4 MB, same region
    float* out = (float*)d_out;

    cvt_kernel<<<384, 256, 0, stream>>>(mlp_w, wb_mlp, 98304);
    cvt_kernel<<<1024, 256, 0, stream>>>(c1w, wb_c1, 262144);
    cvt_kernel<<<1024, 256, 0, stream>>>(c2w, wb_c2, 262144);
    knn_part_kernel<<<dim3(32, 8, 8), 256, 0, stream>>>(xyz1, xyz2, cand);
    knn_merge_kernel<<<256, 256, 0, stream>>>(cand, idx, wgt);
    tr_kernel<<<dim3(128, 2, 8), 256, 0, stream>>>(points1, p1t, 128, 8192);
    tr_kernel<<<dim3(32, 4, 8), 256, 0, stream>>>(points2, p2t, 256, 2048);
    build_x0_kernel<<<dim3(128, 8), 256, 0, stream>>>(p1t, p2t, idx, wgt, X0t);
    film_kernel<<<dim3(8, 2), 256, 0, stream>>>(t_emb, c_emb, tw, tb, cw, cb, film);
    // stage 1: conv(384->256) + GN(gs=32) + SiLU  -> identity X
    gemm_kernel<<<dim3(64, 2, 8), 256, 0, stream>>>(X0t, wb_mlp, mlp_b, Y1t, part0, 384, 256, 5);
    gn_reduce_kernel<<<1, 128, 0, stream>>>(part0, stats0);
    gn_act2_kernel<<<512, 256, 0, stream>>>(Y1t, mlp_gw, mlp_gb, stats0, 5, 5, 1.f / (32.f * 8192.f));
    // stage 2: conv(256->1024) + GN(gs=128) + SiLU
    gemm_kernel<<<dim3(64, 8, 8), 256, 0, stream>>>(Y1t, wb_c1, c1b, H1t, part1, 256, 1024, 7);
    gn_reduce_kernel<<<1, 128, 0, stream>>>(part1, stats1);
    gn_act2_kernel<<<2048, 256, 0, stream>>>(H1t, g1w, g1b, stats1, 7, 7, 1.f / (128.f * 8192.f));
    // stage 3: conv(1024->256); GN2 + FiLM + residual fused into final
    gemm_kernel<<<dim3(64, 2, 8), 256, 0, stream>>>(H1t, wb_c2, c2b, Y2t, part2, 1024, 256, 5);
    gn_reduce_kernel<<<1, 128, 0, stream>>>(part2, stats2);
    final_kernel<<<dim3(128, 8), 256, 0, stream>>>(Y2t, Y1t, g2w, g2b, stats2, film, out);
}